// Round 1
// baseline (2065.083 us; speedup 1.0000x reference)
//
#include <hip/hip_runtime.h>
#include <math.h>

// Problem constants (fixed by the reference)
#define NN   20000
#define EE   320000
#define FF   256
#define HH   64
#define NHEADS 4
#define DHH  64      // per-head dim of TransformerConv
#define LLAY 3
#define GG   64
#define CCLS 10

// ---------------------------------------------------------------------------
// CSR build: histogram of dst, exclusive scan, scatter src ids sorted by dst
// ---------------------------------------------------------------------------
__global__ void k_hist(const int* __restrict__ dst, int E, int* __restrict__ counts) {
    int i = blockIdx.x * blockDim.x + threadIdx.x;
    if (i < E) atomicAdd(&counts[dst[i]], 1);
}

__global__ void k_scan(const int* __restrict__ counts, int N,
                       int* __restrict__ indptr, int* __restrict__ cursor) {
    __shared__ int sdata[1024];
    __shared__ int soff;
    int t = threadIdx.x;
    if (t == 0) soff = 0;
    __syncthreads();
    for (int base = 0; base < N; base += 1024) {
        int v = (base + t < N) ? counts[base + t] : 0;
        sdata[t] = v;
        __syncthreads();
        for (int off = 1; off < 1024; off <<= 1) {
            int x = (t >= off) ? sdata[t - off] : 0;
            __syncthreads();
            sdata[t] += x;
            __syncthreads();
        }
        int incl = sdata[t];
        int excl = incl - v;
        if (base + t < N) { indptr[base + t] = soff + excl; cursor[base + t] = soff + excl; }
        __syncthreads();
        if (t == 1023) soff += incl;
        __syncthreads();
    }
    if (t == 0) indptr[N] = soff;
}

__global__ void k_scatter(const int* __restrict__ src, const int* __restrict__ dst, int E,
                          int* __restrict__ cursor, int* __restrict__ srcs) {
    int i = blockIdx.x * blockDim.x + threadIdx.x;
    if (i < E) {
        int p = atomicAdd(&cursor[dst[i]], 1);
        srcs[p] = src[i];
    }
}

// ---------------------------------------------------------------------------
// Embedding: h = x @ W_emb + b_emb + temp_emb[t]   ([N,256] @ [256,64])
// One block per node, 64 threads (one per output feature).
// ---------------------------------------------------------------------------
__global__ void k_embed(const float* __restrict__ x, const float* __restrict__ W,
                        const float* __restrict__ b, const float* __restrict__ temb,
                        float* __restrict__ h) {
    int n = blockIdx.x;
    int j = threadIdx.x;  // 0..63
    __shared__ float xs[FF];
    for (int i = j; i < FF; i += 64) xs[i] = x[n * FF + i];
    __syncthreads();
    float acc = b[j] + temb[j];
#pragma unroll 8
    for (int f = 0; f < FF; ++f) acc += xs[f] * W[f * HH + j];
    h[n * HH + j] = acc;
}

// ---------------------------------------------------------------------------
// Per-layer projections: qkv[n,0:768] = h[n,:] @ [Wq|Wk|Wv] + b,
// skip[n,0:64] = h[n,:] @ Ws + bs.  One block per node, 256 threads.
// ---------------------------------------------------------------------------
__global__ void k_qkvs(const float* __restrict__ h,
                       const float* __restrict__ Wq, const float* __restrict__ bq,
                       const float* __restrict__ Wk, const float* __restrict__ bk,
                       const float* __restrict__ Wv, const float* __restrict__ bv,
                       const float* __restrict__ Ws, const float* __restrict__ bs,
                       float* __restrict__ qkv, float* __restrict__ skip) {
    int n = blockIdx.x;
    int t = threadIdx.x;  // 0..255
    __shared__ float hs[HH];
    if (t < HH) hs[t] = h[n * HH + t];
    __syncthreads();
    float aq = bq[t], ak = bk[t], av = bv[t];
#pragma unroll 8
    for (int f = 0; f < HH; ++f) {
        float hf = hs[f];
        aq += hf * Wq[f * 256 + t];
        ak += hf * Wk[f * 256 + t];
        av += hf * Wv[f * 256 + t];
    }
    qkv[n * 768 + t]       = aq;
    qkv[n * 768 + 256 + t] = ak;
    qkv[n * 768 + 512 + t] = av;
    if (t < HH) {
        float as = bs[t];
#pragma unroll 8
        for (int f = 0; f < HH; ++f) as += hs[f] * Ws[f * HH + t];
        skip[n * HH + t] = as;
    }
}

// ---------------------------------------------------------------------------
// Attention aggregate per node. 4 waves per block, wave = head, lane = dim.
// Online softmax over incident edges (CSR, dst-sorted). Then head-mean +
// skip + relu.
// ---------------------------------------------------------------------------
__global__ void k_attn(const float* __restrict__ qkv, const float* __restrict__ skip,
                       const int* __restrict__ indptr, const int* __restrict__ srcs,
                       float* __restrict__ hout) {
    int n = blockIdx.x;
    int t = threadIdx.x;           // 0..255
    int lane = t & 63;
    int wid = t >> 6;              // head 0..3
    int beg = indptr[n], end = indptr[n + 1];
    float q = qkv[n * 768 + wid * 64 + lane];
    float m = -INFINITY, s = 0.f, acc = 0.f;
    for (int e = beg; e < end; ++e) {
        int src = srcs[e];
        const float* kv = qkv + (size_t)src * 768 + 256 + wid * 64;
        float kd = kv[lane];
        float dot = q * kd;
#pragma unroll
        for (int off = 1; off < 64; off <<= 1) dot += __shfl_xor(dot, off);
        float logit = dot * 0.125f;  // 1/sqrt(64)
        float mn = fmaxf(m, logit);
        float scale = __expf(m - mn);      // exp(-inf)=0 on first edge
        float p = __expf(logit - mn);
        s = s * scale + p;
        acc = acc * scale + p * kv[256 + lane];  // v element
        m = mn;
    }
    __shared__ float aggs[NHEADS][64];
    aggs[wid][lane] = (end > beg) ? (acc / s) : 0.f;
    __syncthreads();
    if (t < HH) {
        float r = 0.25f * (aggs[0][t] + aggs[1][t] + aggs[2][t] + aggs[3][t]) + skip[n * HH + t];
        hout[n * HH + t] = fmaxf(r, 0.f);
    }
}

// ---------------------------------------------------------------------------
// Mean pool per graph (batch sorted, but atomics are fine within tolerance)
// ---------------------------------------------------------------------------
__global__ void k_pool(const float* __restrict__ h, const int* __restrict__ batch,
                       float* __restrict__ pooled, float* __restrict__ cnt) {
    int n = blockIdx.x;
    int j = threadIdx.x;  // 0..63
    int g = batch[n];
    atomicAdd(&pooled[g * HH + j], h[n * HH + j]);
    if (j == 0) atomicAdd(&cnt[g], 1.f);
}

// ---------------------------------------------------------------------------
// Head: per graph g: mean-pool finalize, MHA over seq=2, mean, classifier.
// One block per graph, 64 threads.
// ---------------------------------------------------------------------------
__global__ void k_head(const float* __restrict__ pooled, const float* __restrict__ cnt,
                       const float* __restrict__ in_w, const float* __restrict__ in_b,
                       const float* __restrict__ out_w, const float* __restrict__ out_b,
                       const float* __restrict__ Wc1, const float* __restrict__ bc1,
                       const float* __restrict__ Wc2, const float* __restrict__ bc2,
                       float* __restrict__ out) {
    int g = blockIdx.x;
    int t = threadIdx.x;  // 0..63
    __shared__ float xs[2][HH];
    __shared__ float qkvs[2][3 * HH];
    __shared__ float sc[2][2][NHEADS];
    __shared__ float os[2][HH];
    __shared__ float xf[HH];
    __shared__ float r1[HH / 2];

    for (int s = 0; s < 2; ++s) {
        float c = fmaxf(cnt[s * GG + g], 1.f);
        xs[s][t] = pooled[(size_t)s * GG * HH + g * HH + t] / c;
    }
    __syncthreads();
    // in-proj: qkv[s][i] = x[s] . in_w[i,:] + in_b[i], i in [0,192)
    for (int idx = t; idx < 2 * 192; idx += 64) {
        int s = idx / 192, i = idx % 192;
        float a = in_b[i];
#pragma unroll 8
        for (int j = 0; j < HH; ++j) a += xs[s][j] * in_w[i * HH + j];
        qkvs[s][i] = a;
    }
    __syncthreads();
    // scores (dh = 16, scale 0.25)
    if (t < 16) {
        int s1 = t >> 3, s2 = (t >> 2) & 1, hh = t & 3;
        float a = 0.f;
#pragma unroll
        for (int d = 0; d < 16; ++d) a += qkvs[s1][hh * 16 + d] * qkvs[s2][HH + hh * 16 + d];
        sc[s1][s2][hh] = a * 0.25f;
    }
    __syncthreads();
    // softmax over keys (2) and o = p0*v0 + p1*v1, per output dim t (head = t>>4)
    {
        int hh = t >> 4;
        for (int s1 = 0; s1 < 2; ++s1) {
            float a0 = sc[s1][0][hh], a1 = sc[s1][1][hh];
            float mx = fmaxf(a0, a1);
            float e0 = __expf(a0 - mx), e1 = __expf(a1 - mx);
            float inv = 1.f / (e0 + e1);
            os[s1][t] = (e0 * inv) * qkvs[0][2 * HH + t] + (e1 * inv) * qkvs[1][2 * HH + t];
        }
    }
    __syncthreads();
    // out-proj + mean over seq
    {
        float acc0 = 0.f, acc1 = 0.f;
#pragma unroll 8
        for (int k2 = 0; k2 < HH; ++k2) {
            float w = out_w[t * HH + k2];
            acc0 += os[0][k2] * w;
            acc1 += os[1][k2] * w;
        }
        xf[t] = 0.5f * (acc0 + acc1) + out_b[t];
    }
    __syncthreads();
    if (t < 32) {
        float a = bc1[t];
#pragma unroll 8
        for (int j = 0; j < HH; ++j) a += xf[j] * Wc1[j * 32 + t];
        r1[t] = fmaxf(a, 0.f);
    }
    __syncthreads();
    if (t < CCLS) {
        float a = bc2[t];
#pragma unroll
        for (int j2 = 0; j2 < 32; ++j2) a += r1[j2] * Wc2[j2 * CCLS + t];
        out[g * CCLS + t] = a;
    }
}

// ---------------------------------------------------------------------------
extern "C" void kernel_launch(void* const* d_in, const int* in_sizes, int n_in,
                              void* d_out, int out_size, void* d_ws, size_t ws_size,
                              hipStream_t stream) {
    const float* x1    = (const float*)d_in[0];
    const float* x2    = (const float*)d_in[1];
    const int*   ei1   = (const int*)d_in[2];
    const int*   ei2   = (const int*)d_in[3];
    const int*   bat1  = (const int*)d_in[4];
    const int*   bat2  = (const int*)d_in[5];
    const float* W_emb = (const float*)d_in[6];
    const float* b_emb = (const float*)d_in[7];
    const float* temb  = (const float*)d_in[8];
    const float* Wq    = (const float*)d_in[9];
    const float* bq    = (const float*)d_in[10];
    const float* Wk    = (const float*)d_in[11];
    const float* bk    = (const float*)d_in[12];
    const float* Wv    = (const float*)d_in[13];
    const float* bv    = (const float*)d_in[14];
    const float* Ws    = (const float*)d_in[15];
    const float* bs    = (const float*)d_in[16];
    const float* miw   = (const float*)d_in[17];
    const float* mib   = (const float*)d_in[18];
    const float* mow   = (const float*)d_in[19];
    const float* mob   = (const float*)d_in[20];
    const float* Wc1   = (const float*)d_in[21];
    const float* bc1   = (const float*)d_in[22];
    const float* Wc2   = (const float*)d_in[23];
    const float* bc2   = (const float*)d_in[24];

    const int N = in_sizes[4];        // 20000
    const int E = in_sizes[2] / 2;    // 320000

    // workspace carve
    char* p = (char*)d_ws;
    auto carve = [&](size_t bytes) {
        void* r = (void*)p;
        p += (bytes + 255) & ~(size_t)255;
        return r;
    };
    float* h      = (float*)carve((size_t)N * HH * 4);
    float* hn     = (float*)carve((size_t)N * HH * 4);
    float* qkv    = (float*)carve((size_t)N * 768 * 4);
    float* skip   = (float*)carve((size_t)N * HH * 4);
    float* pooled = (float*)carve(2 * GG * HH * 4);
    float* cnt    = (float*)carve(2 * GG * 4);
    int*   counts = (int*)carve((size_t)N * 4);
    int*   indptr = (int*)carve((size_t)(N + 1) * 4);
    int*   cursor = (int*)carve((size_t)N * 4);
    int*   srcs   = (int*)carve((size_t)E * 4);

    hipMemsetAsync(pooled, 0, 2 * GG * HH * 4, stream);
    hipMemsetAsync(cnt, 0, 2 * GG * 4, stream);

    for (int b = 0; b < 2; ++b) {
        const float* x     = b ? x2 : x1;
        const int*   ei    = b ? ei2 : ei1;
        const int*   batch = b ? bat2 : bat1;

        // CSR build (dst-sorted)
        hipMemsetAsync(counts, 0, (size_t)N * 4, stream);
        k_hist<<<(E + 255) / 256, 256, 0, stream>>>(ei + E, E, counts);
        k_scan<<<1, 1024, 0, stream>>>(counts, N, indptr, cursor);
        k_scatter<<<(E + 255) / 256, 256, 0, stream>>>(ei, ei + E, E, cursor, srcs);

        // embedding
        k_embed<<<N, 64, 0, stream>>>(x, W_emb, b_emb, temb + b * HH, h);

        float* cur = h;
        float* nxt = hn;
        for (int l = 0; l < LLAY; ++l) {
            k_qkvs<<<N, 256, 0, stream>>>(cur,
                                          Wq + (size_t)l * HH * 256, bq + (size_t)l * 256,
                                          Wk + (size_t)l * HH * 256, bk + (size_t)l * 256,
                                          Wv + (size_t)l * HH * 256, bv + (size_t)l * 256,
                                          Ws + (size_t)l * HH * HH,  bs + (size_t)l * HH,
                                          qkv, skip);
            k_attn<<<N, 256, 0, stream>>>(qkv, skip, indptr, srcs, nxt);
            float* tmp = cur; cur = nxt; nxt = tmp;
        }
        k_pool<<<N, 64, 0, stream>>>(cur, batch, pooled + (size_t)b * GG * HH, cnt + (size_t)b * GG);
    }

    k_head<<<GG, 64, 0, stream>>>(pooled, cnt, miw, mib, mow, mob, Wc1, bc1, Wc2, bc2,
                                  (float*)d_out);
}

// Round 2
// 1006.983 us; speedup vs baseline: 2.0508x; 2.0508x over previous
//
#include <hip/hip_runtime.h>
#include <math.h>

// Problem constants (fixed by the reference)
#define NN   20000
#define EE   320000
#define FF   256
#define HH   64
#define NHEADS 4
#define DHH  64
#define LLAY 3
#define GG   64
#define CCLS 10

// ---------------------------------------------------------------------------
// CSR build: histogram of dst, exclusive scan, scatter src ids sorted by dst
// ---------------------------------------------------------------------------
__global__ void k_hist(const int* __restrict__ dst, int E, int* __restrict__ counts) {
    int i = blockIdx.x * blockDim.x + threadIdx.x;
    if (i < E) atomicAdd(&counts[dst[i]], 1);
}

__global__ void k_scan(const int* __restrict__ counts, int N,
                       int* __restrict__ indptr, int* __restrict__ cursor) {
    __shared__ int sdata[1024];
    __shared__ int soff;
    int t = threadIdx.x;
    if (t == 0) soff = 0;
    __syncthreads();
    for (int base = 0; base < N; base += 1024) {
        int v = (base + t < N) ? counts[base + t] : 0;
        sdata[t] = v;
        __syncthreads();
        for (int off = 1; off < 1024; off <<= 1) {
            int x = (t >= off) ? sdata[t - off] : 0;
            __syncthreads();
            sdata[t] += x;
            __syncthreads();
        }
        int incl = sdata[t];
        int excl = incl - v;
        if (base + t < N) { indptr[base + t] = soff + excl; cursor[base + t] = soff + excl; }
        __syncthreads();
        if (t == 1023) soff += incl;
        __syncthreads();
    }
    if (t == 0) indptr[N] = soff;
}

__global__ void k_scatter(const int* __restrict__ src, const int* __restrict__ dst, int E,
                          int* __restrict__ cursor, int* __restrict__ srcs) {
    int i = blockIdx.x * blockDim.x + threadIdx.x;
    if (i < E) {
        int p = atomicAdd(&cursor[dst[i]], 1);
        srcs[p] = src[i];
    }
}

// ---------------------------------------------------------------------------
// Embedding: h = x @ W_emb + b_emb + temp_emb[t]   ([N,256] @ [256,64])
// 16 nodes per block, 256 threads: thread t -> col j=t&63, node group (t>>6)*4.
// ---------------------------------------------------------------------------
__global__ void k_embed(const float* __restrict__ x, const float* __restrict__ W,
                        const float* __restrict__ b, const float* __restrict__ temb,
                        float* __restrict__ h, int N) {
    __shared__ float xsT[FF * 16];  // [f][n] 16KB
    int t = threadIdx.x;
    int node_base = blockIdx.x * 16;
    // load x tile transposed
    for (int r = 0; r < 16; ++r) {
        int i = r * 256 + t;          // 0..4095
        int nl = i >> 8, f = i & 255;
        int node = node_base + nl;
        xsT[f * 16 + nl] = (node < N) ? x[(size_t)node * FF + f] : 0.f;
    }
    __syncthreads();
    int j = t & 63;
    int ng = (t >> 6) * 4;            // first of 4 nodes handled by this thread
    float bias = b[j] + temb[j];
    float a0 = bias, a1 = bias, a2 = bias, a3 = bias;
    for (int f = 0; f < FF; ++f) {
        float w = W[f * HH + j];
        const float4* hp = reinterpret_cast<const float4*>(&xsT[f * 16 + ng]);
        float4 hv = hp[0];
        a0 += hv.x * w; a1 += hv.y * w; a2 += hv.z * w; a3 += hv.w * w;
    }
    if (node_base + ng + 0 < N) h[(size_t)(node_base + ng + 0) * HH + j] = a0;
    if (node_base + ng + 1 < N) h[(size_t)(node_base + ng + 1) * HH + j] = a1;
    if (node_base + ng + 2 < N) h[(size_t)(node_base + ng + 2) * HH + j] = a2;
    if (node_base + ng + 3 < N) h[(size_t)(node_base + ng + 3) * HH + j] = a3;
}

// ---------------------------------------------------------------------------
// Projections for one layer: qkv[n,768], skip[n,64].
// 16 nodes per block, 256 threads; thread t owns column t of Wq/Wk/Wv.
// Each W element feeds 16 FMAs -> 16x less L2 weight traffic than 1-node/blk.
// ---------------------------------------------------------------------------
__global__ void k_proj(const float* __restrict__ h,
                       const float* __restrict__ Wq, const float* __restrict__ bq,
                       const float* __restrict__ Wk, const float* __restrict__ bk,
                       const float* __restrict__ Wv, const float* __restrict__ bv,
                       const float* __restrict__ Ws, const float* __restrict__ bs,
                       float* __restrict__ qkv, float* __restrict__ skip, int N) {
    __shared__ float hsT[HH * 16];    // [f][n] 4KB
    int t = threadIdx.x;
    int node_base = blockIdx.x * 16;
    for (int r = 0; r < 4; ++r) {
        int i = r * 256 + t;          // 0..1023
        int nl = i >> 6, f = i & 63;
        int node = node_base + nl;
        hsT[f * 16 + nl] = (node < N) ? h[(size_t)node * HH + f] : 0.f;
    }
    __syncthreads();

    float accq[16], acck[16], accv[16];
    float vbq = bq[t], vbk = bk[t], vbv = bv[t];
#pragma unroll
    for (int n = 0; n < 16; ++n) { accq[n] = vbq; acck[n] = vbk; accv[n] = vbv; }

    for (int f = 0; f < HH; ++f) {
        float wq = Wq[f * 256 + t];
        float wk = Wk[f * 256 + t];
        float wv = Wv[f * 256 + t];
        const float4* hp = reinterpret_cast<const float4*>(&hsT[f * 16]);
        float4 h0 = hp[0], h1 = hp[1], h2 = hp[2], h3 = hp[3];
        float hv[16] = {h0.x,h0.y,h0.z,h0.w, h1.x,h1.y,h1.z,h1.w,
                        h2.x,h2.y,h2.z,h2.w, h3.x,h3.y,h3.z,h3.w};
#pragma unroll
        for (int n = 0; n < 16; ++n) {
            accq[n] += hv[n] * wq;
            acck[n] += hv[n] * wk;
            accv[n] += hv[n] * wv;
        }
    }
#pragma unroll
    for (int n = 0; n < 16; ++n) {
        int node = node_base + n;
        if (node < N) {
            qkv[(size_t)node * 768 + t]       = accq[n];
            qkv[(size_t)node * 768 + 256 + t] = acck[n];
            qkv[(size_t)node * 768 + 512 + t] = accv[n];
        }
    }
    // skip = h @ Ws + bs (64 cols): wave 0 only
    if (t < HH) {
        float accs[16];
        float vbs = bs[t];
#pragma unroll
        for (int n = 0; n < 16; ++n) accs[n] = vbs;
        for (int f = 0; f < HH; ++f) {
            float ws = Ws[f * HH + t];
            const float4* hp = reinterpret_cast<const float4*>(&hsT[f * 16]);
            float4 h0 = hp[0], h1 = hp[1], h2 = hp[2], h3 = hp[3];
            float hv[16] = {h0.x,h0.y,h0.z,h0.w, h1.x,h1.y,h1.z,h1.w,
                            h2.x,h2.y,h2.z,h2.w, h3.x,h3.y,h3.z,h3.w};
#pragma unroll
            for (int n = 0; n < 16; ++n) accs[n] += hv[n] * ws;
        }
#pragma unroll
        for (int n = 0; n < 16; ++n) {
            int node = node_base + n;
            if (node < N) skip[(size_t)node * HH + t] = accs[n];
        }
    }
}

// ---------------------------------------------------------------------------
// Attention aggregate. One WAVE per node, all 4 heads at once:
// lane l -> head (l>>4), dims 4*(l&15)..+3 (float4). Online softmax.
// Then head-mean via 2 butterfly steps + skip + relu.
// ---------------------------------------------------------------------------
__global__ void k_attn(const float* __restrict__ qkv, const float* __restrict__ skip,
                       const int* __restrict__ indptr, const int* __restrict__ srcs,
                       float* __restrict__ hout, int N) {
    int t = threadIdx.x;              // 0..255
    int lane = t & 63;
    int wv = t >> 6;
    int n = blockIdx.x * 4 + wv;
    if (n >= N) return;
    int hd = lane >> 4;
    int d0 = (lane & 15) * 4;
    int off = hd * 64 + d0;

    const float4 q4 = *reinterpret_cast<const float4*>(&qkv[(size_t)n * 768 + off]);
    int beg = indptr[n], end = indptr[n + 1];
    float m = -INFINITY, s = 0.f;
    float ax = 0.f, ay = 0.f, az = 0.f, aw = 0.f;
    for (int e = beg; e < end; ++e) {
        int src = srcs[e];
        const float* base = qkv + (size_t)src * 768 + 256;
        float4 k4 = *reinterpret_cast<const float4*>(base + off);
        float dot = q4.x * k4.x + q4.y * k4.y + q4.z * k4.z + q4.w * k4.w;
#pragma unroll
        for (int o = 1; o < 16; o <<= 1) dot += __shfl_xor(dot, o);
        float logit = dot * 0.125f;
        float mn = fmaxf(m, logit);
        float sc = __expf(m - mn);       // exp(-inf)=0 first edge
        float p = __expf(logit - mn);
        s = s * sc + p;
        float4 v4 = *reinterpret_cast<const float4*>(base + 256 + off);
        ax = ax * sc + p * v4.x;
        ay = ay * sc + p * v4.y;
        az = az * sc + p * v4.z;
        aw = aw * sc + p * v4.w;
        m = mn;
    }
    float inv = (end > beg) ? 1.f / s : 0.f;
    ax *= inv; ay *= inv; az *= inv; aw *= inv;
    // head mean: sum across the 4 head groups (lanes differing in bits 4,5)
#pragma unroll
    for (int o = 16; o < 64; o <<= 1) {
        ax += __shfl_xor(ax, o);
        ay += __shfl_xor(ay, o);
        az += __shfl_xor(az, o);
        aw += __shfl_xor(aw, o);
    }
    if (lane < 16) {
        const float4 sk = *reinterpret_cast<const float4*>(&skip[(size_t)n * HH + d0]);
        float4 r;
        r.x = fmaxf(0.25f * ax + sk.x, 0.f);
        r.y = fmaxf(0.25f * ay + sk.y, 0.f);
        r.z = fmaxf(0.25f * az + sk.z, 0.f);
        r.w = fmaxf(0.25f * aw + sk.w, 0.f);
        *reinterpret_cast<float4*>(&hout[(size_t)n * HH + d0]) = r;
    }
}

// ---------------------------------------------------------------------------
// Mean pool: batch is sorted -> run-length accumulate 32 nodes per block,
// flush ~2 atomics per lane instead of 32.
// ---------------------------------------------------------------------------
__global__ void k_pool(const float* __restrict__ h, const int* __restrict__ batch,
                       float* __restrict__ pooled, float* __restrict__ cnt, int N) {
    int j = threadIdx.x;              // 0..63
    int n0 = blockIdx.x * 32;
    int n1 = min(n0 + 32, N);
    if (n0 >= N) return;
    float acc = 0.f;
    int c = 0;
    int gcur = batch[n0];
    for (int n = n0; n < n1; ++n) {
        int g = batch[n];
        if (g != gcur) {
            atomicAdd(&pooled[gcur * HH + j], acc);
            if (j == 0) atomicAdd(&cnt[gcur], (float)c);
            acc = 0.f; c = 0; gcur = g;
        }
        acc += h[(size_t)n * HH + j];
        ++c;
    }
    atomicAdd(&pooled[gcur * HH + j], acc);
    if (j == 0) atomicAdd(&cnt[gcur], (float)c);
}

// ---------------------------------------------------------------------------
// Head: mean-pool finalize, MHA over seq=2, mean, classifier. Block per graph.
// ---------------------------------------------------------------------------
__global__ void k_head(const float* __restrict__ pooled, const float* __restrict__ cnt,
                       const float* __restrict__ in_w, const float* __restrict__ in_b,
                       const float* __restrict__ out_w, const float* __restrict__ out_b,
                       const float* __restrict__ Wc1, const float* __restrict__ bc1,
                       const float* __restrict__ Wc2, const float* __restrict__ bc2,
                       float* __restrict__ out) {
    int g = blockIdx.x;
    int t = threadIdx.x;  // 0..63
    __shared__ float xs[2][HH];
    __shared__ float qkvs[2][3 * HH];
    __shared__ float sc[2][2][NHEADS];
    __shared__ float os[2][HH];
    __shared__ float xf[HH];
    __shared__ float r1[HH / 2];

    for (int s = 0; s < 2; ++s) {
        float c = fmaxf(cnt[s * GG + g], 1.f);
        xs[s][t] = pooled[(size_t)s * GG * HH + g * HH + t] / c;
    }
    __syncthreads();
    for (int idx = t; idx < 2 * 192; idx += 64) {
        int s = idx / 192, i = idx % 192;
        float a = in_b[i];
#pragma unroll 8
        for (int j = 0; j < HH; ++j) a += xs[s][j] * in_w[i * HH + j];
        qkvs[s][i] = a;
    }
    __syncthreads();
    if (t < 16) {
        int s1 = t >> 3, s2 = (t >> 2) & 1, hh = t & 3;
        float a = 0.f;
#pragma unroll
        for (int d = 0; d < 16; ++d) a += qkvs[s1][hh * 16 + d] * qkvs[s2][HH + hh * 16 + d];
        sc[s1][s2][hh] = a * 0.25f;
    }
    __syncthreads();
    {
        int hh = t >> 4;
        for (int s1 = 0; s1 < 2; ++s1) {
            float a0 = sc[s1][0][hh], a1 = sc[s1][1][hh];
            float mx = fmaxf(a0, a1);
            float e0 = __expf(a0 - mx), e1 = __expf(a1 - mx);
            float inv = 1.f / (e0 + e1);
            os[s1][t] = (e0 * inv) * qkvs[0][2 * HH + t] + (e1 * inv) * qkvs[1][2 * HH + t];
        }
    }
    __syncthreads();
    {
        float acc0 = 0.f, acc1 = 0.f;
#pragma unroll 8
        for (int k2 = 0; k2 < HH; ++k2) {
            float w = out_w[t * HH + k2];
            acc0 += os[0][k2] * w;
            acc1 += os[1][k2] * w;
        }
        xf[t] = 0.5f * (acc0 + acc1) + out_b[t];
    }
    __syncthreads();
    if (t < 32) {
        float a = bc1[t];
#pragma unroll 8
        for (int j = 0; j < HH; ++j) a += xf[j] * Wc1[j * 32 + t];
        r1[t] = fmaxf(a, 0.f);
    }
    __syncthreads();
    if (t < CCLS) {
        float a = bc2[t];
#pragma unroll
        for (int j2 = 0; j2 < 32; ++j2) a += r1[j2] * Wc2[j2 * CCLS + t];
        out[g * CCLS + t] = a;
    }
}

// ---------------------------------------------------------------------------
extern "C" void kernel_launch(void* const* d_in, const int* in_sizes, int n_in,
                              void* d_out, int out_size, void* d_ws, size_t ws_size,
                              hipStream_t stream) {
    const float* x1    = (const float*)d_in[0];
    const float* x2    = (const float*)d_in[1];
    const int*   ei1   = (const int*)d_in[2];
    const int*   ei2   = (const int*)d_in[3];
    const int*   bat1  = (const int*)d_in[4];
    const int*   bat2  = (const int*)d_in[5];
    const float* W_emb = (const float*)d_in[6];
    const float* b_emb = (const float*)d_in[7];
    const float* temb  = (const float*)d_in[8];
    const float* Wq    = (const float*)d_in[9];
    const float* bq    = (const float*)d_in[10];
    const float* Wk    = (const float*)d_in[11];
    const float* bk    = (const float*)d_in[12];
    const float* Wv    = (const float*)d_in[13];
    const float* bv    = (const float*)d_in[14];
    const float* Ws    = (const float*)d_in[15];
    const float* bs    = (const float*)d_in[16];
    const float* miw   = (const float*)d_in[17];
    const float* mib   = (const float*)d_in[18];
    const float* mow   = (const float*)d_in[19];
    const float* mob   = (const float*)d_in[20];
    const float* Wc1   = (const float*)d_in[21];
    const float* bc1   = (const float*)d_in[22];
    const float* Wc2   = (const float*)d_in[23];
    const float* bc2   = (const float*)d_in[24];

    const int N = in_sizes[4];        // 20000
    const int E = in_sizes[2] / 2;    // 320000

    char* p = (char*)d_ws;
    auto carve = [&](size_t bytes) {
        void* r = (void*)p;
        p += (bytes + 255) & ~(size_t)255;
        return r;
    };
    float* h      = (float*)carve((size_t)N * HH * 4);
    float* hn     = (float*)carve((size_t)N * HH * 4);
    float* qkv    = (float*)carve((size_t)N * 768 * 4);
    float* skip   = (float*)carve((size_t)N * HH * 4);
    float* pooled = (float*)carve(2 * GG * HH * 4);
    float* cnt    = (float*)carve(2 * GG * 4);
    int*   counts = (int*)carve((size_t)N * 4);
    int*   indptr = (int*)carve((size_t)(N + 1) * 4);
    int*   cursor = (int*)carve((size_t)N * 4);
    int*   srcs   = (int*)carve((size_t)E * 4);

    hipMemsetAsync(pooled, 0, 2 * GG * HH * 4, stream);
    hipMemsetAsync(cnt, 0, 2 * GG * 4, stream);

    const int nodeBlocks16 = (N + 15) / 16;

    for (int b = 0; b < 2; ++b) {
        const float* x     = b ? x2 : x1;
        const int*   ei    = b ? ei2 : ei1;
        const int*   batch = b ? bat2 : bat1;

        hipMemsetAsync(counts, 0, (size_t)N * 4, stream);
        k_hist<<<(E + 255) / 256, 256, 0, stream>>>(ei + E, E, counts);
        k_scan<<<1, 1024, 0, stream>>>(counts, N, indptr, cursor);
        k_scatter<<<(E + 255) / 256, 256, 0, stream>>>(ei, ei + E, E, cursor, srcs);

        k_embed<<<nodeBlocks16, 256, 0, stream>>>(x, W_emb, b_emb, temb + b * HH, h, N);

        float* cur = h;
        float* nxt = hn;
        for (int l = 0; l < LLAY; ++l) {
            k_proj<<<nodeBlocks16, 256, 0, stream>>>(cur,
                                          Wq + (size_t)l * HH * 256, bq + (size_t)l * 256,
                                          Wk + (size_t)l * HH * 256, bk + (size_t)l * 256,
                                          Wv + (size_t)l * HH * 256, bv + (size_t)l * 256,
                                          Ws + (size_t)l * HH * HH,  bs + (size_t)l * HH,
                                          qkv, skip, N);
            k_attn<<<(N + 3) / 4, 256, 0, stream>>>(qkv, skip, indptr, srcs, nxt, N);
            float* tmp = cur; cur = nxt; nxt = tmp;
        }
        k_pool<<<(N + 31) / 32, 64, 0, stream>>>(cur, batch,
                                                 pooled + (size_t)b * GG * HH, cnt + (size_t)b * GG, N);
    }

    k_head<<<GG, 64, 0, stream>>>(pooled, cnt, miw, mib, mow, mob, Wc1, bc1, Wc2, bc2,
                                  (float*)d_out);
}

// Round 3
// 863.492 us; speedup vs baseline: 2.3915x; 1.1662x over previous
//
#include <hip/hip_runtime.h>
#include <math.h>

// Problem constants (fixed by the reference)
#define NN   20000
#define EE   320000
#define FF   256
#define HH   64
#define NHEADS 4
#define DHH  64
#define LLAY 3
#define GG   64
#define CCLS 10

__device__ __forceinline__ unsigned short f2bf(float f) {
    unsigned int u = __float_as_uint(f);
    unsigned int r = (u + 0x7fffu + ((u >> 16) & 1u)) >> 16;   // RNE
    return (unsigned short)r;
}

// ---------------------------------------------------------------------------
// CSR build: histogram of dst, exclusive scan, scatter src ids sorted by dst
// ---------------------------------------------------------------------------
__global__ void k_hist(const int* __restrict__ dst, int E, int* __restrict__ counts) {
    int i = blockIdx.x * blockDim.x + threadIdx.x;
    if (i < E) atomicAdd(&counts[dst[i]], 1);
}

__global__ void k_scan(const int* __restrict__ counts, int N,
                       int* __restrict__ indptr, int* __restrict__ cursor) {
    __shared__ int sdata[1024];
    __shared__ int soff;
    int t = threadIdx.x;
    if (t == 0) soff = 0;
    __syncthreads();
    for (int base = 0; base < N; base += 1024) {
        int v = (base + t < N) ? counts[base + t] : 0;
        sdata[t] = v;
        __syncthreads();
        for (int off = 1; off < 1024; off <<= 1) {
            int x = (t >= off) ? sdata[t - off] : 0;
            __syncthreads();
            sdata[t] += x;
            __syncthreads();
        }
        int incl = sdata[t];
        int excl = incl - v;
        if (base + t < N) { indptr[base + t] = soff + excl; cursor[base + t] = soff + excl; }
        __syncthreads();
        if (t == 1023) soff += incl;
        __syncthreads();
    }
    if (t == 0) indptr[N] = soff;
}

__global__ void k_scatter(const int* __restrict__ src, const int* __restrict__ dst, int E,
                          int* __restrict__ cursor, int* __restrict__ srcs) {
    int i = blockIdx.x * blockDim.x + threadIdx.x;
    if (i < E) {
        int p = atomicAdd(&cursor[dst[i]], 1);
        srcs[p] = src[i];
    }
}

// ---------------------------------------------------------------------------
// Embedding: h = x @ W_emb + b_emb + temp_emb[t]   ([N,256] @ [256,64])
// 16 nodes/block. LDS tile xs[16][256] (row-major: stride-1 b128 writes,
// broadcast b128 reads -> conflict-free).
// ---------------------------------------------------------------------------
__global__ void k_embed(const float* __restrict__ x, const float* __restrict__ W,
                        const float* __restrict__ b, const float* __restrict__ temb,
                        float* __restrict__ h, int N) {
    __shared__ float xs[16][FF];  // 16KB
    int t = threadIdx.x;
    int node_base = blockIdx.x * 16;
#pragma unroll
    for (int r = 0; r < 4; ++r) {
        int v = r * 256 + t;            // float4 index in tile
        int nl = v >> 6, fq = v & 63;
        int node = node_base + nl;
        float4 val = make_float4(0.f, 0.f, 0.f, 0.f);
        if (node < N) val = *reinterpret_cast<const float4*>(&x[(size_t)node * FF + fq * 4]);
        *reinterpret_cast<float4*>(&xs[nl][fq * 4]) = val;
    }
    __syncthreads();
    int j = t & 63;
    int ng = (t >> 6) * 4;
    float bias = b[j] + temb[j];
    float a0 = bias, a1 = bias, a2 = bias, a3 = bias;
    for (int f = 0; f < FF; f += 4) {
        float w0 = W[(f + 0) * HH + j];
        float w1 = W[(f + 1) * HH + j];
        float w2 = W[(f + 2) * HH + j];
        float w3 = W[(f + 3) * HH + j];
        float4 x0 = *reinterpret_cast<const float4*>(&xs[ng + 0][f]);
        float4 x1 = *reinterpret_cast<const float4*>(&xs[ng + 1][f]);
        float4 x2 = *reinterpret_cast<const float4*>(&xs[ng + 2][f]);
        float4 x3 = *reinterpret_cast<const float4*>(&xs[ng + 3][f]);
        a0 += x0.x * w0 + x0.y * w1 + x0.z * w2 + x0.w * w3;
        a1 += x1.x * w0 + x1.y * w1 + x1.z * w2 + x1.w * w3;
        a2 += x2.x * w0 + x2.y * w1 + x2.z * w2 + x2.w * w3;
        a3 += x3.x * w0 + x3.y * w1 + x3.z * w2 + x3.w * w3;
    }
    if (node_base + ng + 0 < N) h[(size_t)(node_base + ng + 0) * HH + j] = a0;
    if (node_base + ng + 1 < N) h[(size_t)(node_base + ng + 1) * HH + j] = a1;
    if (node_base + ng + 2 < N) h[(size_t)(node_base + ng + 2) * HH + j] = a2;
    if (node_base + ng + 3 < N) h[(size_t)(node_base + ng + 3) * HH + j] = a3;
}

// ---------------------------------------------------------------------------
// Projections: q[n,256] fp32, kv[n, K256|V256] bf16, skip[n,64] fp32.
// 16 nodes/block, 256 threads; thread t owns output column t.
// LDS tile hs[16][64] row-major (conflict-free writes, broadcast reads).
// ---------------------------------------------------------------------------
__global__ void k_proj(const float* __restrict__ h,
                       const float* __restrict__ Wq, const float* __restrict__ bq,
                       const float* __restrict__ Wk, const float* __restrict__ bk,
                       const float* __restrict__ Wv, const float* __restrict__ bv,
                       const float* __restrict__ Ws, const float* __restrict__ bs,
                       float* __restrict__ qout, unsigned short* __restrict__ kvb,
                       float* __restrict__ skip, int N) {
    __shared__ float hs[16][HH];      // 4KB
    int t = threadIdx.x;
    int node_base = blockIdx.x * 16;
    {
        int nl = t >> 4, fq = t & 15;  // 256 float4 in tile, one per thread
        int node = node_base + nl;
        float4 val = make_float4(0.f, 0.f, 0.f, 0.f);
        if (node < N) val = *reinterpret_cast<const float4*>(&h[(size_t)node * HH + fq * 4]);
        *reinterpret_cast<float4*>(&hs[nl][fq * 4]) = val;
    }
    __syncthreads();

    float accq[16], acck[16], accv[16];
    float vbq = bq[t], vbk = bk[t], vbv = bv[t];
#pragma unroll
    for (int n = 0; n < 16; ++n) { accq[n] = vbq; acck[n] = vbk; accv[n] = vbv; }

    for (int f = 0; f < HH; f += 4) {
        float wq0 = Wq[(f + 0) * 256 + t], wq1 = Wq[(f + 1) * 256 + t];
        float wq2 = Wq[(f + 2) * 256 + t], wq3 = Wq[(f + 3) * 256 + t];
        float wk0 = Wk[(f + 0) * 256 + t], wk1 = Wk[(f + 1) * 256 + t];
        float wk2 = Wk[(f + 2) * 256 + t], wk3 = Wk[(f + 3) * 256 + t];
        float wv0 = Wv[(f + 0) * 256 + t], wv1 = Wv[(f + 1) * 256 + t];
        float wv2 = Wv[(f + 2) * 256 + t], wv3 = Wv[(f + 3) * 256 + t];
#pragma unroll
        for (int n = 0; n < 16; ++n) {
            float4 hx = *reinterpret_cast<const float4*>(&hs[n][f]);
            accq[n] += hx.x * wq0 + hx.y * wq1 + hx.z * wq2 + hx.w * wq3;
            acck[n] += hx.x * wk0 + hx.y * wk1 + hx.z * wk2 + hx.w * wk3;
            accv[n] += hx.x * wv0 + hx.y * wv1 + hx.z * wv2 + hx.w * wv3;
        }
    }
#pragma unroll
    for (int n = 0; n < 16; ++n) {
        int node = node_base + n;
        if (node < N) {
            qout[(size_t)node * 256 + t] = accq[n];
            kvb[(size_t)node * 512 + t]       = f2bf(acck[n]);
            kvb[(size_t)node * 512 + 256 + t] = f2bf(accv[n]);
        }
    }
    if (t < HH) {
        float accs[16];
        float vbs = bs[t];
#pragma unroll
        for (int n = 0; n < 16; ++n) accs[n] = vbs;
        for (int f = 0; f < HH; f += 4) {
            float w0 = Ws[(f + 0) * HH + t], w1 = Ws[(f + 1) * HH + t];
            float w2 = Ws[(f + 2) * HH + t], w3 = Ws[(f + 3) * HH + t];
#pragma unroll
            for (int n = 0; n < 16; ++n) {
                float4 hx = *reinterpret_cast<const float4*>(&hs[n][f]);
                accs[n] += hx.x * w0 + hx.y * w1 + hx.z * w2 + hx.w * w3;
            }
        }
#pragma unroll
        for (int n = 0; n < 16; ++n) {
            int node = node_base + n;
            if (node < N) skip[(size_t)node * HH + t] = accs[n];
        }
    }
}

// ---------------------------------------------------------------------------
// Attention aggregate. One WAVE per node, all 4 heads:
// lane l -> head (l>>4), dims 4*(l&15). K/V gathers are bf16 (8B per lane).
// Chunked (8-edge) online softmax: all 16 gathers of a chunk issue before
// any dependent compute -> latency overlap.
// ---------------------------------------------------------------------------
__global__ void k_attn(const float* __restrict__ qarr, const unsigned short* __restrict__ kvb,
                       const float* __restrict__ skip,
                       const int* __restrict__ indptr, const int* __restrict__ srcs,
                       float* __restrict__ hout, int N) {
    int t = threadIdx.x;
    int lane = t & 63;
    int wv = t >> 6;
    int n = blockIdx.x * 4 + wv;
    if (n >= N) return;
    int hd = lane >> 4;
    int d0 = (lane & 15) * 4;
    int off = hd * 64 + d0;     // element offset within a 256-elem K (or V) row

    const float4 q4 = *reinterpret_cast<const float4*>(&qarr[(size_t)n * 256 + off]);
    int beg = indptr[n], end = indptr[n + 1];
    float m = -INFINITY, s = 0.f;
    float ax = 0.f, ay = 0.f, az = 0.f, aw = 0.f;

    for (int e = beg; e < end; e += 8) {
        int c = end - e; if (c > 8) c = 8;
        uint2 kk[8], vv[8];
        // phase 1: issue all gathers
#pragma unroll
        for (int i = 0; i < 8; ++i) {
            if (i < c) {
                const unsigned short* base = kvb + (size_t)srcs[e + i] * 512 + off;
                kk[i] = *reinterpret_cast<const uint2*>(base);
                vv[i] = *reinterpret_cast<const uint2*>(base + 256);
            } else {
                kk[i] = make_uint2(0u, 0u);
                vv[i] = make_uint2(0u, 0u);
            }
        }
        // phase 2: dots + 16-lane reduces (8 independent chains)
        float lg[8];
#pragma unroll
        for (int i = 0; i < 8; ++i) {
            float k0 = __uint_as_float(kk[i].x << 16);
            float k1 = __uint_as_float(kk[i].x & 0xffff0000u);
            float k2 = __uint_as_float(kk[i].y << 16);
            float k3 = __uint_as_float(kk[i].y & 0xffff0000u);
            float dot = q4.x * k0 + q4.y * k1 + q4.z * k2 + q4.w * k3;
#pragma unroll
            for (int o = 1; o < 16; o <<= 1) dot += __shfl_xor(dot, o);
            lg[i] = (i < c) ? dot * 0.125f : -INFINITY;
        }
        // phase 3: chunk softmax update
        float cm = lg[0];
#pragma unroll
        for (int i = 1; i < 8; ++i) cm = fmaxf(cm, lg[i]);
        float mn = fmaxf(m, cm);
        float rs = __expf(m - mn);          // exp(-inf)=0 on first chunk
        s *= rs; ax *= rs; ay *= rs; az *= rs; aw *= rs;
#pragma unroll
        for (int i = 0; i < 8; ++i) {
            float p = __expf(lg[i] - mn);
            s += p;
            float v0 = __uint_as_float(vv[i].x << 16);
            float v1 = __uint_as_float(vv[i].x & 0xffff0000u);
            float v2 = __uint_as_float(vv[i].y << 16);
            float v3 = __uint_as_float(vv[i].y & 0xffff0000u);
            ax += p * v0; ay += p * v1; az += p * v2; aw += p * v3;
        }
        m = mn;
    }
    float inv = (end > beg) ? 1.f / s : 0.f;
    ax *= inv; ay *= inv; az *= inv; aw *= inv;
#pragma unroll
    for (int o = 16; o < 64; o <<= 1) {
        ax += __shfl_xor(ax, o);
        ay += __shfl_xor(ay, o);
        az += __shfl_xor(az, o);
        aw += __shfl_xor(aw, o);
    }
    if (lane < 16) {
        const float4 sk = *reinterpret_cast<const float4*>(&skip[(size_t)n * HH + d0]);
        float4 r;
        r.x = fmaxf(0.25f * ax + sk.x, 0.f);
        r.y = fmaxf(0.25f * ay + sk.y, 0.f);
        r.z = fmaxf(0.25f * az + sk.z, 0.f);
        r.w = fmaxf(0.25f * aw + sk.w, 0.f);
        *reinterpret_cast<float4*>(&hout[(size_t)n * HH + d0]) = r;
    }
}

// ---------------------------------------------------------------------------
// Mean pool: batch sorted -> run-length accumulate 32 nodes per block.
// ---------------------------------------------------------------------------
__global__ void k_pool(const float* __restrict__ h, const int* __restrict__ batch,
                       float* __restrict__ pooled, float* __restrict__ cnt, int N) {
    int j = threadIdx.x;
    int n0 = blockIdx.x * 32;
    int n1 = min(n0 + 32, N);
    if (n0 >= N) return;
    float acc = 0.f;
    int c = 0;
    int gcur = batch[n0];
    for (int n = n0; n < n1; ++n) {
        int g = batch[n];
        if (g != gcur) {
            atomicAdd(&pooled[gcur * HH + j], acc);
            if (j == 0) atomicAdd(&cnt[gcur], (float)c);
            acc = 0.f; c = 0; gcur = g;
        }
        acc += h[(size_t)n * HH + j];
        ++c;
    }
    atomicAdd(&pooled[gcur * HH + j], acc);
    if (j == 0) atomicAdd(&cnt[gcur], (float)c);
}

// ---------------------------------------------------------------------------
// Head: mean-pool finalize, MHA over seq=2, mean, classifier. Block per graph.
// ---------------------------------------------------------------------------
__global__ void k_head(const float* __restrict__ pooled, const float* __restrict__ cnt,
                       const float* __restrict__ in_w, const float* __restrict__ in_b,
                       const float* __restrict__ out_w, const float* __restrict__ out_b,
                       const float* __restrict__ Wc1, const float* __restrict__ bc1,
                       const float* __restrict__ Wc2, const float* __restrict__ bc2,
                       float* __restrict__ out) {
    int g = blockIdx.x;
    int t = threadIdx.x;  // 0..63
    __shared__ float xs[2][HH];
    __shared__ float qkvs[2][3 * HH];
    __shared__ float sc[2][2][NHEADS];
    __shared__ float os[2][HH];
    __shared__ float xf[HH];
    __shared__ float r1[HH / 2];

    for (int s = 0; s < 2; ++s) {
        float c = fmaxf(cnt[s * GG + g], 1.f);
        xs[s][t] = pooled[(size_t)s * GG * HH + g * HH + t] / c;
    }
    __syncthreads();
    for (int idx = t; idx < 2 * 192; idx += 64) {
        int s = idx / 192, i = idx % 192;
        float a = in_b[i];
#pragma unroll 8
        for (int j = 0; j < HH; ++j) a += xs[s][j] * in_w[i * HH + j];
        qkvs[s][i] = a;
    }
    __syncthreads();
    if (t < 16) {
        int s1 = t >> 3, s2 = (t >> 2) & 1, hh = t & 3;
        float a = 0.f;
#pragma unroll
        for (int d = 0; d < 16; ++d) a += qkvs[s1][hh * 16 + d] * qkvs[s2][HH + hh * 16 + d];
        sc[s1][s2][hh] = a * 0.25f;
    }
    __syncthreads();
    {
        int hh = t >> 4;
        for (int s1 = 0; s1 < 2; ++s1) {
            float a0 = sc[s1][0][hh], a1 = sc[s1][1][hh];
            float mx = fmaxf(a0, a1);
            float e0 = __expf(a0 - mx), e1 = __expf(a1 - mx);
            float inv = 1.f / (e0 + e1);
            os[s1][t] = (e0 * inv) * qkvs[0][2 * HH + t] + (e1 * inv) * qkvs[1][2 * HH + t];
        }
    }
    __syncthreads();
    {
        float acc0 = 0.f, acc1 = 0.f;
#pragma unroll 8
        for (int k2 = 0; k2 < HH; ++k2) {
            float w = out_w[t * HH + k2];
            acc0 += os[0][k2] * w;
            acc1 += os[1][k2] * w;
        }
        xf[t] = 0.5f * (acc0 + acc1) + out_b[t];
    }
    __syncthreads();
    if (t < 32) {
        float a = bc1[t];
#pragma unroll 8
        for (int j = 0; j < HH; ++j) a += xf[j] * Wc1[j * 32 + t];
        r1[t] = fmaxf(a, 0.f);
    }
    __syncthreads();
    if (t < CCLS) {
        float a = bc2[t];
#pragma unroll
        for (int j2 = 0; j2 < 32; ++j2) a += r1[j2] * Wc2[j2 * CCLS + t];
        out[g * CCLS + t] = a;
    }
}

// ---------------------------------------------------------------------------
extern "C" void kernel_launch(void* const* d_in, const int* in_sizes, int n_in,
                              void* d_out, int out_size, void* d_ws, size_t ws_size,
                              hipStream_t stream) {
    const float* x1    = (const float*)d_in[0];
    const float* x2    = (const float*)d_in[1];
    const int*   ei1   = (const int*)d_in[2];
    const int*   ei2   = (const int*)d_in[3];
    const int*   bat1  = (const int*)d_in[4];
    const int*   bat2  = (const int*)d_in[5];
    const float* W_emb = (const float*)d_in[6];
    const float* b_emb = (const float*)d_in[7];
    const float* temb  = (const float*)d_in[8];
    const float* Wq    = (const float*)d_in[9];
    const float* bq    = (const float*)d_in[10];
    const float* Wk    = (const float*)d_in[11];
    const float* bk    = (const float*)d_in[12];
    const float* Wv    = (const float*)d_in[13];
    const float* bv    = (const float*)d_in[14];
    const float* Ws    = (const float*)d_in[15];
    const float* bs    = (const float*)d_in[16];
    const float* miw   = (const float*)d_in[17];
    const float* mib   = (const float*)d_in[18];
    const float* mow   = (const float*)d_in[19];
    const float* mob   = (const float*)d_in[20];
    const float* Wc1   = (const float*)d_in[21];
    const float* bc1   = (const float*)d_in[22];
    const float* Wc2   = (const float*)d_in[23];
    const float* bc2   = (const float*)d_in[24];

    const int N = in_sizes[4];        // 20000
    const int E = in_sizes[2] / 2;    // 320000

    char* p = (char*)d_ws;
    auto carve = [&](size_t bytes) {
        void* r = (void*)p;
        p += (bytes + 255) & ~(size_t)255;
        return r;
    };
    float*          h      = (float*)carve((size_t)N * HH * 4);
    float*          hn     = (float*)carve((size_t)N * HH * 4);
    float*          qarr   = (float*)carve((size_t)N * 256 * 4);
    unsigned short* kvb    = (unsigned short*)carve((size_t)N * 512 * 2);
    float*          skip   = (float*)carve((size_t)N * HH * 4);
    float*          pooled = (float*)carve(2 * GG * HH * 4);
    float*          cnt    = (float*)carve(2 * GG * 4);
    int*            counts = (int*)carve((size_t)N * 4);
    int*            indptr = (int*)carve((size_t)(N + 1) * 4);
    int*            cursor = (int*)carve((size_t)N * 4);
    int*            srcs   = (int*)carve((size_t)E * 4);

    hipMemsetAsync(pooled, 0, 2 * GG * HH * 4, stream);
    hipMemsetAsync(cnt, 0, 2 * GG * 4, stream);

    const int nodeBlocks16 = (N + 15) / 16;

    for (int b = 0; b < 2; ++b) {
        const float* x     = b ? x2 : x1;
        const int*   ei    = b ? ei2 : ei1;
        const int*   batch = b ? bat2 : bat1;

        hipMemsetAsync(counts, 0, (size_t)N * 4, stream);
        k_hist<<<(E + 255) / 256, 256, 0, stream>>>(ei + E, E, counts);
        k_scan<<<1, 1024, 0, stream>>>(counts, N, indptr, cursor);
        k_scatter<<<(E + 255) / 256, 256, 0, stream>>>(ei, ei + E, E, cursor, srcs);

        k_embed<<<nodeBlocks16, 256, 0, stream>>>(x, W_emb, b_emb, temb + b * HH, h, N);

        float* cur = h;
        float* nxt = hn;
        for (int l = 0; l < LLAY; ++l) {
            k_proj<<<nodeBlocks16, 256, 0, stream>>>(cur,
                                          Wq + (size_t)l * HH * 256, bq + (size_t)l * 256,
                                          Wk + (size_t)l * HH * 256, bk + (size_t)l * 256,
                                          Wv + (size_t)l * HH * 256, bv + (size_t)l * 256,
                                          Ws + (size_t)l * HH * HH,  bs + (size_t)l * HH,
                                          qarr, kvb, skip, N);
            k_attn<<<(N + 3) / 4, 256, 0, stream>>>(qarr, kvb, skip, indptr, srcs, nxt, N);
            float* tmp = cur; cur = nxt; nxt = tmp;
        }
        k_pool<<<(N + 31) / 32, 64, 0, stream>>>(cur, batch,
                                                 pooled + (size_t)b * GG * HH, cnt + (size_t)b * GG, N);
    }

    k_head<<<GG, 64, 0, stream>>>(pooled, cnt, miw, mib, mow, mob, Wc1, bc1, Wc2, bc2,
                                  (float*)d_out);
}

// Round 4
// 655.359 us; speedup vs baseline: 3.1511x; 1.3176x over previous
//
#include <hip/hip_runtime.h>
#include <math.h>

#define FF   256
#define HH   64
#define NHEADS 4
#define LLAY 3
#define GG   64
#define CCLS 10

typedef __attribute__((ext_vector_type(8))) short short8v;
typedef __attribute__((ext_vector_type(4))) float floatx4;

__device__ __forceinline__ unsigned short f2bf(float f) {
    unsigned int u = __float_as_uint(f);
    unsigned int r = (u + 0x7fffu + ((u >> 16) & 1u)) >> 16;   // RNE
    return (unsigned short)r;
}
__device__ __forceinline__ float bf2f(unsigned short h) {
    return __uint_as_float((unsigned int)h << 16);
}

// ---------------------------------------------------------------------------
// Weight packing (once per launch).
// Proj panel per layer: [2(hi/lo)][832 cols][64 k] bf16. cols = Wq|Wk|Wv|Ws.
// ---------------------------------------------------------------------------
__global__ void k_packw(const float* __restrict__ Wq, const float* __restrict__ Wk,
                        const float* __restrict__ Wv, const float* __restrict__ Ws,
                        unsigned short* __restrict__ panel) {
    int idx = blockIdx.x * 256 + threadIdx.x;          // over 3*832*64
    if (idx >= 3 * 832 * 64) return;
    int l = idx / (832 * 64);
    int rem = idx % (832 * 64);
    int c = rem / 64, k = rem % 64;
    float v;
    if (c < 256)      v = Wq[((size_t)l * 64 + k) * 256 + c];
    else if (c < 512) v = Wk[((size_t)l * 64 + k) * 256 + (c - 256)];
    else if (c < 768) v = Wv[((size_t)l * 64 + k) * 256 + (c - 512)];
    else              v = Ws[((size_t)l * 64 + k) * 64 + (c - 768)];
    unsigned short hi = f2bf(v);
    unsigned short lo = f2bf(v - bf2f(hi));
    panel[((size_t)l * 2 + 0) * 832 * 64 + rem] = hi;
    panel[((size_t)l * 2 + 1) * 832 * 64 + rem] = lo;
}

// Embed panel: [2][64 cols][256 k] bf16 from W_emb[256][64]
__global__ void k_packemb(const float* __restrict__ W, unsigned short* __restrict__ pE) {
    int idx = blockIdx.x * 256 + threadIdx.x;          // over 64*256
    if (idx >= 64 * 256) return;
    int c = idx / 256, k = idx % 256;
    float v = W[(size_t)k * 64 + c];
    unsigned short hi = f2bf(v);
    unsigned short lo = f2bf(v - bf2f(hi));
    pE[idx] = hi;
    pE[64 * 256 + idx] = lo;
}

// ---------------------------------------------------------------------------
// CSR build (branch = blockIdx.y)
// ---------------------------------------------------------------------------
__global__ void k_hist(const int* __restrict__ eiA, const int* __restrict__ eiB, int E,
                       int* __restrict__ counts, size_t sC) {
    int br = blockIdx.y;
    const int* dst = (br ? eiB : eiA) + E;
    int* c = counts + (size_t)br * sC;
    int i = blockIdx.x * blockDim.x + threadIdx.x;
    if (i < E) atomicAdd(&c[dst[i]], 1);
}

__global__ void k_scan(const int* __restrict__ counts0, int N,
                       int* __restrict__ indptr0, int* __restrict__ cursor0,
                       size_t sC, size_t sP) {
    int br = blockIdx.y;
    const int* counts = counts0 + (size_t)br * sC;
    int* indptr = indptr0 + (size_t)br * sP;
    int* cursor = cursor0 + (size_t)br * sC;
    __shared__ int sdata[1024];
    __shared__ int soff;
    int t = threadIdx.x;
    if (t == 0) soff = 0;
    __syncthreads();
    for (int base = 0; base < N; base += 1024) {
        int v = (base + t < N) ? counts[base + t] : 0;
        sdata[t] = v;
        __syncthreads();
        for (int off = 1; off < 1024; off <<= 1) {
            int x = (t >= off) ? sdata[t - off] : 0;
            __syncthreads();
            sdata[t] += x;
            __syncthreads();
        }
        int incl = sdata[t];
        int excl = incl - v;
        if (base + t < N) { indptr[base + t] = soff + excl; cursor[base + t] = soff + excl; }
        __syncthreads();
        if (t == 1023) soff += incl;
        __syncthreads();
    }
    if (t == 0) indptr[N] = soff;
}

__global__ void k_scatter(const int* __restrict__ eiA, const int* __restrict__ eiB, int E,
                          int* __restrict__ cursor0, int* __restrict__ srcs0,
                          size_t sC, size_t sE) {
    int br = blockIdx.y;
    const int* ei = br ? eiB : eiA;
    int* cursor = cursor0 + (size_t)br * sC;
    int* srcs = srcs0 + (size_t)br * sE;
    int i = blockIdx.x * blockDim.x + threadIdx.x;
    if (i < E) {
        int p = atomicAdd(&cursor[ei[E + i]], 1);
        srcs[p] = ei[i];
    }
}

// ---------------------------------------------------------------------------
// Embedding MFMA: h = x @ W_emb + b + temb.  M=32/block, 4 waves = 4 N-tiles.
// bf16x3 split for fp32-equivalent accuracy.
// ---------------------------------------------------------------------------
__global__ void k_embed(const float* __restrict__ xa, const float* __restrict__ xb,
                        const unsigned short* __restrict__ pE,
                        const float* __restrict__ bemb, const float* __restrict__ temb,
                        float* __restrict__ hbuf, int N, size_t sH) {
    int br = blockIdx.y;
    const float* x = br ? xb : xa;
    float* h = hbuf + (size_t)br * sH;
    int t = threadIdx.x, lane = t & 63, wid = t >> 6;
    int arow = lane & 15, kg = lane >> 4;
    int mbase = blockIdx.x * 32;
    int n0 = min(mbase + arow, N - 1);
    int n1 = min(mbase + 16 + arow, N - 1);
    const float* x0 = x + (size_t)n0 * FF + kg * 8;
    const float* x1 = x + (size_t)n1 * FF + kg * 8;
    const unsigned short* bh = pE + (size_t)(wid * 16 + arow) * FF + kg * 8;
    const unsigned short* bl = bh + 64 * FF;
    floatx4 acc0 = {0.f, 0.f, 0.f, 0.f}, acc1 = {0.f, 0.f, 0.f, 0.f};
#pragma unroll
    for (int ks = 0; ks < 8; ++ks) {
        const float4* p0 = reinterpret_cast<const float4*>(x0 + ks * 32);
        float4 f00 = p0[0], f01 = p0[1];
        const float4* p1 = reinterpret_cast<const float4*>(x1 + ks * 32);
        float4 f10 = p1[0], f11 = p1[1];
        float v0[8] = {f00.x, f00.y, f00.z, f00.w, f01.x, f01.y, f01.z, f01.w};
        float v1[8] = {f10.x, f10.y, f10.z, f10.w, f11.x, f11.y, f11.z, f11.w};
        short8v a0h, a0l, a1h, a1l;
#pragma unroll
        for (int i = 0; i < 8; ++i) {
            unsigned short h0 = f2bf(v0[i]);
            a0h[i] = (short)h0; a0l[i] = (short)f2bf(v0[i] - bf2f(h0));
            unsigned short h1 = f2bf(v1[i]);
            a1h[i] = (short)h1; a1l[i] = (short)f2bf(v1[i] - bf2f(h1));
        }
        short8v bhv = *reinterpret_cast<const short8v*>(bh + ks * 32);
        short8v blv = *reinterpret_cast<const short8v*>(bl + ks * 32);
        acc0 = __builtin_amdgcn_mfma_f32_16x16x32_bf16(a0h, bhv, acc0, 0, 0, 0);
        acc0 = __builtin_amdgcn_mfma_f32_16x16x32_bf16(a0l, bhv, acc0, 0, 0, 0);
        acc0 = __builtin_amdgcn_mfma_f32_16x16x32_bf16(a0h, blv, acc0, 0, 0, 0);
        acc1 = __builtin_amdgcn_mfma_f32_16x16x32_bf16(a1h, bhv, acc1, 0, 0, 0);
        acc1 = __builtin_amdgcn_mfma_f32_16x16x32_bf16(a1l, bhv, acc1, 0, 0, 0);
        acc1 = __builtin_amdgcn_mfma_f32_16x16x32_bf16(a1h, blv, acc1, 0, 0, 0);
    }
    int col = wid * 16 + (lane & 15);
    float bias = bemb[col] + temb[(size_t)br * HH + col];
#pragma unroll
    for (int r = 0; r < 4; ++r) {
        int row0 = mbase + kg * 4 + r;
        if (row0 < N) h[(size_t)row0 * HH + col] = acc0[r] + bias;
        int row1 = mbase + 16 + kg * 4 + r;
        if (row1 < N) h[(size_t)row1 * HH + col] = acc1[r] + bias;
    }
}

// ---------------------------------------------------------------------------
// Projection MFMA: [q|k|v|skip] = h @ panel + bias. M=32/block, 4 waves × 13
// N-tiles each (N=832). q,k,v stored bf16; skip fp32.
// ---------------------------------------------------------------------------
__global__ void k_proj(const float* __restrict__ hbuf, const unsigned short* __restrict__ panel,
                       const float* __restrict__ bq, const float* __restrict__ bk,
                       const float* __restrict__ bv, const float* __restrict__ bs,
                       unsigned short* __restrict__ qb0, unsigned short* __restrict__ kvb0,
                       float* __restrict__ skip0, int N,
                       size_t sH, size_t sQ, size_t sKV, size_t sS) {
    int br = blockIdx.y;
    const float* h = hbuf + (size_t)br * sH;
    unsigned short* q = qb0 + (size_t)br * sQ;
    unsigned short* kv = kvb0 + (size_t)br * sKV;
    float* sk = skip0 + (size_t)br * sS;
    int t = threadIdx.x, lane = t & 63, wid = t >> 6;
    int arow = lane & 15, kg = lane >> 4;
    int mbase = blockIdx.x * 32;

    short8v Ah[2][2], Al[2][2];
#pragma unroll
    for (int mt = 0; mt < 2; ++mt) {
        int node = min(mbase + mt * 16 + arow, N - 1);
        const float* src = h + (size_t)node * HH + kg * 8;
#pragma unroll
        for (int ks = 0; ks < 2; ++ks) {
            const float4* pp = reinterpret_cast<const float4*>(src + ks * 32);
            float4 fa = pp[0], fb = pp[1];
            float v[8] = {fa.x, fa.y, fa.z, fa.w, fb.x, fb.y, fb.z, fb.w};
#pragma unroll
            for (int i = 0; i < 8; ++i) {
                unsigned short hi = f2bf(v[i]);
                Ah[mt][ks][i] = (short)hi;
                Al[mt][ks][i] = (short)f2bf(v[i] - bf2f(hi));
            }
        }
    }
    const unsigned short* ph = panel;
    const unsigned short* pl = panel + 832 * 64;
#pragma unroll
    for (int j = 0; j < 13; ++j) {
        int nt = wid * 13 + j;
        size_t boff = (size_t)(nt * 16 + arow) * 64 + kg * 8;
        floatx4 acc0 = {0.f, 0.f, 0.f, 0.f}, acc1 = {0.f, 0.f, 0.f, 0.f};
#pragma unroll
        for (int ks = 0; ks < 2; ++ks) {
            short8v bh = *reinterpret_cast<const short8v*>(ph + boff + ks * 32);
            short8v bl = *reinterpret_cast<const short8v*>(pl + boff + ks * 32);
            acc0 = __builtin_amdgcn_mfma_f32_16x16x32_bf16(Ah[0][ks], bh, acc0, 0, 0, 0);
            acc0 = __builtin_amdgcn_mfma_f32_16x16x32_bf16(Al[0][ks], bh, acc0, 0, 0, 0);
            acc0 = __builtin_amdgcn_mfma_f32_16x16x32_bf16(Ah[0][ks], bl, acc0, 0, 0, 0);
            acc1 = __builtin_amdgcn_mfma_f32_16x16x32_bf16(Ah[1][ks], bh, acc1, 0, 0, 0);
            acc1 = __builtin_amdgcn_mfma_f32_16x16x32_bf16(Al[1][ks], bh, acc1, 0, 0, 0);
            acc1 = __builtin_amdgcn_mfma_f32_16x16x32_bf16(Ah[1][ks], bl, acc1, 0, 0, 0);
        }
        int col = nt * 16 + (lane & 15);
        float bias;
        if (col < 256) bias = bq[col];
        else if (col < 512) bias = bk[col - 256];
        else if (col < 768) bias = bv[col - 512];
        else bias = bs[col - 768];

        auto store_tile = [&](const floatx4& acc, int mrow0) {
#pragma unroll
            for (int r = 0; r < 4; ++r) {
                int node = mrow0 + kg * 4 + r;
                if (node < N) {
                    float val = acc[r] + bias;
                    if (col < 256)      q[(size_t)node * 256 + col] = f2bf(val);
                    else if (col < 512) kv[(size_t)node * 512 + (col - 256)] = f2bf(val);
                    else if (col < 768) kv[(size_t)node * 512 + 256 + (col - 512)] = f2bf(val);
                    else                sk[(size_t)node * HH + (col - 768)] = val;
                }
            }
        };
        store_tile(acc0, mbase);
        store_tile(acc1, mbase + 16);
    }
}

// ---------------------------------------------------------------------------
// Attention aggregate. One wave per node, 4 heads; bf16 q/k/v; 8-edge chunks.
// Writes relu(head_mean + skip) in place over h.
// ---------------------------------------------------------------------------
__global__ void k_attn(const unsigned short* __restrict__ qb0, const unsigned short* __restrict__ kvb0,
                       const float* __restrict__ skip0,
                       const int* __restrict__ indptr0, const int* __restrict__ srcs0,
                       float* __restrict__ hout0, int N,
                       size_t sQ, size_t sKV, size_t sS, size_t sH, size_t sP, size_t sE) {
    int br = blockIdx.y;
    const unsigned short* qb = qb0 + (size_t)br * sQ;
    const unsigned short* kvb = kvb0 + (size_t)br * sKV;
    const float* skip = skip0 + (size_t)br * sS;
    const int* indptr = indptr0 + (size_t)br * sP;
    const int* srcs = srcs0 + (size_t)br * sE;
    float* hout = hout0 + (size_t)br * sH;

    int t = threadIdx.x;
    int lane = t & 63;
    int wv = t >> 6;
    int n = blockIdx.x * 4 + wv;
    if (n >= N) return;
    int hd = lane >> 4;
    int d0 = (lane & 15) * 4;
    int off = hd * 64 + d0;

    uint2 qraw = *reinterpret_cast<const uint2*>(qb + (size_t)n * 256 + off);
    float qx = bf2f((unsigned short)(qraw.x & 0xffffu));
    float qy = __uint_as_float(qraw.x & 0xffff0000u);
    float qz = bf2f((unsigned short)(qraw.y & 0xffffu));
    float qw = __uint_as_float(qraw.y & 0xffff0000u);

    int beg = indptr[n], end = indptr[n + 1];
    float m = -INFINITY, s = 0.f;
    float ax = 0.f, ay = 0.f, az = 0.f, aw = 0.f;

    for (int e = beg; e < end; e += 8) {
        int c = end - e; if (c > 8) c = 8;
        uint2 kk[8], vv[8];
#pragma unroll
        for (int i = 0; i < 8; ++i) {
            if (i < c) {
                const unsigned short* base = kvb + (size_t)srcs[e + i] * 512 + off;
                kk[i] = *reinterpret_cast<const uint2*>(base);
                vv[i] = *reinterpret_cast<const uint2*>(base + 256);
            } else {
                kk[i] = make_uint2(0u, 0u);
                vv[i] = make_uint2(0u, 0u);
            }
        }
        float lg[8];
#pragma unroll
        for (int i = 0; i < 8; ++i) {
            float k0 = __uint_as_float(kk[i].x << 16);
            float k1 = __uint_as_float(kk[i].x & 0xffff0000u);
            float k2 = __uint_as_float(kk[i].y << 16);
            float k3 = __uint_as_float(kk[i].y & 0xffff0000u);
            float dot = qx * k0 + qy * k1 + qz * k2 + qw * k3;
#pragma unroll
            for (int o = 1; o < 16; o <<= 1) dot += __shfl_xor(dot, o);
            lg[i] = (i < c) ? dot * 0.125f : -INFINITY;
        }
        float cm = lg[0];
#pragma unroll
        for (int i = 1; i < 8; ++i) cm = fmaxf(cm, lg[i]);
        float mn = fmaxf(m, cm);
        float rs = __expf(m - mn);
        s *= rs; ax *= rs; ay *= rs; az *= rs; aw *= rs;
#pragma unroll
        for (int i = 0; i < 8; ++i) {
            float p = __expf(lg[i] - mn);
            s += p;
            float v0 = __uint_as_float(vv[i].x << 16);
            float v1 = __uint_as_float(vv[i].x & 0xffff0000u);
            float v2 = __uint_as_float(vv[i].y << 16);
            float v3 = __uint_as_float(vv[i].y & 0xffff0000u);
            ax += p * v0; ay += p * v1; az += p * v2; aw += p * v3;
        }
        m = mn;
    }
    float inv = (end > beg) ? 1.f / s : 0.f;
    ax *= inv; ay *= inv; az *= inv; aw *= inv;
#pragma unroll
    for (int o = 16; o < 64; o <<= 1) {
        ax += __shfl_xor(ax, o);
        ay += __shfl_xor(ay, o);
        az += __shfl_xor(az, o);
        aw += __shfl_xor(aw, o);
    }
    if (lane < 16) {
        const float4 skv = *reinterpret_cast<const float4*>(&skip[(size_t)n * HH + d0]);
        float4 r;
        r.x = fmaxf(0.25f * ax + skv.x, 0.f);
        r.y = fmaxf(0.25f * ay + skv.y, 0.f);
        r.z = fmaxf(0.25f * az + skv.z, 0.f);
        r.w = fmaxf(0.25f * aw + skv.w, 0.f);
        *reinterpret_cast<float4*>(&hout[(size_t)n * HH + d0]) = r;
    }
}

// ---------------------------------------------------------------------------
// Mean pool (batch sorted, run-length accumulate)
// ---------------------------------------------------------------------------
__global__ void k_pool(const float* __restrict__ hbuf, const int* __restrict__ batA,
                       const int* __restrict__ batB,
                       float* __restrict__ pooled, float* __restrict__ cnt, int N,
                       size_t sH, int brBase) {
    int br = blockIdx.y;
    const float* h = hbuf + (size_t)br * sH;
    const int* batch = br ? batB : batA;
    float* pb = pooled + (size_t)(brBase + br) * GG * HH;
    float* cb = cnt + (size_t)(brBase + br) * GG;
    int j = threadIdx.x;
    int n0 = blockIdx.x * 32;
    int n1 = min(n0 + 32, N);
    if (n0 >= N) return;
    float acc = 0.f;
    int c = 0;
    int gcur = batch[n0];
    for (int n = n0; n < n1; ++n) {
        int g = batch[n];
        if (g != gcur) {
            atomicAdd(&pb[gcur * HH + j], acc);
            if (j == 0) atomicAdd(&cb[gcur], (float)c);
            acc = 0.f; c = 0; gcur = g;
        }
        acc += h[(size_t)n * HH + j];
        ++c;
    }
    atomicAdd(&pb[gcur * HH + j], acc);
    if (j == 0) atomicAdd(&cb[gcur], (float)c);
}

// ---------------------------------------------------------------------------
// Head: mean-pool finalize, MHA over seq=2, mean, classifier. Block per graph.
// ---------------------------------------------------------------------------
__global__ void k_head(const float* __restrict__ pooled, const float* __restrict__ cnt,
                       const float* __restrict__ in_w, const float* __restrict__ in_b,
                       const float* __restrict__ out_w, const float* __restrict__ out_b,
                       const float* __restrict__ Wc1, const float* __restrict__ bc1,
                       const float* __restrict__ Wc2, const float* __restrict__ bc2,
                       float* __restrict__ out) {
    int g = blockIdx.x;
    int t = threadIdx.x;
    __shared__ float xs[2][HH];
    __shared__ float qkvs[2][3 * HH];
    __shared__ float sc[2][2][NHEADS];
    __shared__ float os[2][HH];
    __shared__ float xf[HH];
    __shared__ float r1[HH / 2];

    for (int s = 0; s < 2; ++s) {
        float c = fmaxf(cnt[s * GG + g], 1.f);
        xs[s][t] = pooled[(size_t)s * GG * HH + g * HH + t] / c;
    }
    __syncthreads();
    for (int idx = t; idx < 2 * 192; idx += 64) {
        int s = idx / 192, i = idx % 192;
        float a = in_b[i];
#pragma unroll 8
        for (int j = 0; j < HH; ++j) a += xs[s][j] * in_w[i * HH + j];
        qkvs[s][i] = a;
    }
    __syncthreads();
    if (t < 16) {
        int s1 = t >> 3, s2 = (t >> 2) & 1, hh = t & 3;
        float a = 0.f;
#pragma unroll
        for (int d = 0; d < 16; ++d) a += qkvs[s1][hh * 16 + d] * qkvs[s2][HH + hh * 16 + d];
        sc[s1][s2][hh] = a * 0.25f;
    }
    __syncthreads();
    {
        int hh = t >> 4;
        for (int s1 = 0; s1 < 2; ++s1) {
            float a0 = sc[s1][0][hh], a1 = sc[s1][1][hh];
            float mx = fmaxf(a0, a1);
            float e0 = __expf(a0 - mx), e1 = __expf(a1 - mx);
            float inv = 1.f / (e0 + e1);
            os[s1][t] = (e0 * inv) * qkvs[0][2 * HH + t] + (e1 * inv) * qkvs[1][2 * HH + t];
        }
    }
    __syncthreads();
    {
        float acc0 = 0.f, acc1 = 0.f;
#pragma unroll 8
        for (int k2 = 0; k2 < HH; ++k2) {
            float w = out_w[t * HH + k2];
            acc0 += os[0][k2] * w;
            acc1 += os[1][k2] * w;
        }
        xf[t] = 0.5f * (acc0 + acc1) + out_b[t];
    }
    __syncthreads();
    if (t < 32) {
        float a = bc1[t];
#pragma unroll 8
        for (int j = 0; j < HH; ++j) a += xf[j] * Wc1[j * 32 + t];
        r1[t] = fmaxf(a, 0.f);
    }
    __syncthreads();
    if (t < CCLS) {
        float a = bc2[t];
#pragma unroll
        for (int j2 = 0; j2 < 32; ++j2) a += r1[j2] * Wc2[j2 * CCLS + t];
        out[g * CCLS + t] = a;
    }
}

// ---------------------------------------------------------------------------
extern "C" void kernel_launch(void* const* d_in, const int* in_sizes, int n_in,
                              void* d_out, int out_size, void* d_ws, size_t ws_size,
                              hipStream_t stream) {
    const float* x1    = (const float*)d_in[0];
    const float* x2    = (const float*)d_in[1];
    const int*   ei1   = (const int*)d_in[2];
    const int*   ei2   = (const int*)d_in[3];
    const int*   bat1  = (const int*)d_in[4];
    const int*   bat2  = (const int*)d_in[5];
    const float* W_emb = (const float*)d_in[6];
    const float* b_emb = (const float*)d_in[7];
    const float* temb  = (const float*)d_in[8];
    const float* Wq    = (const float*)d_in[9];
    const float* bq    = (const float*)d_in[10];
    const float* Wk    = (const float*)d_in[11];
    const float* bk    = (const float*)d_in[12];
    const float* Wv    = (const float*)d_in[13];
    const float* bv    = (const float*)d_in[14];
    const float* Ws    = (const float*)d_in[15];
    const float* bs    = (const float*)d_in[16];
    const float* miw   = (const float*)d_in[17];
    const float* mib   = (const float*)d_in[18];
    const float* mow   = (const float*)d_in[19];
    const float* mob   = (const float*)d_in[20];
    const float* Wc1   = (const float*)d_in[21];
    const float* bc1   = (const float*)d_in[22];
    const float* Wc2   = (const float*)d_in[23];
    const float* bc2   = (const float*)d_in[24];

    const int N = in_sizes[4];        // 20000
    const int E = in_sizes[2] / 2;    // 320000

    // sizing: dual mode needs 2x the per-branch buffers
    auto total_for = [&](int NB) -> size_t {
        auto al = [](size_t b) { return (b + 255) & ~(size_t)255; };
        size_t s = 0;
        s += al((size_t)NB * N * 256 * 2);       // qb
        s += al((size_t)NB * N * 512 * 2);       // kvb
        s += al((size_t)NB * N * HH * 4);        // h
        s += al((size_t)NB * N * HH * 4);        // skip
        s += al(2 * GG * HH * 4);                // pooled
        s += al(2 * GG * 4);                     // cnt
        s += al((size_t)NB * N * 4);             // counts
        s += al((size_t)NB * (N + 1) * 4);       // indptr
        s += al((size_t)NB * N * 4);             // cursor
        s += al((size_t)NB * E * 4);             // srcs
        s += al((size_t)3 * 2 * 832 * 64 * 2);   // panel
        s += al((size_t)2 * 64 * 256 * 2);       // panelE
        return s;
    };
    bool dual = ws_size >= total_for(2);
    const int NB = dual ? 2 : 1;

    char* p = (char*)d_ws;
    auto carve = [&](size_t bytes) {
        void* r = (void*)p;
        p += (bytes + 255) & ~(size_t)255;
        return r;
    };
    unsigned short* qb     = (unsigned short*)carve((size_t)NB * N * 256 * 2);
    unsigned short* kvb    = (unsigned short*)carve((size_t)NB * N * 512 * 2);
    float*          h      = (float*)carve((size_t)NB * N * HH * 4);
    float*          skip   = (float*)carve((size_t)NB * N * HH * 4);
    float*          pooled = (float*)carve(2 * GG * HH * 4);
    float*          cnt    = (float*)carve(2 * GG * 4);
    int*            counts = (int*)carve((size_t)NB * N * 4);
    int*            indptr = (int*)carve((size_t)NB * (N + 1) * 4);
    int*            cursor = (int*)carve((size_t)NB * N * 4);
    int*            srcs   = (int*)carve((size_t)NB * E * 4);
    unsigned short* panel  = (unsigned short*)carve((size_t)3 * 2 * 832 * 64 * 2);
    unsigned short* panelE = (unsigned short*)carve((size_t)2 * 64 * 256 * 2);

    hipMemsetAsync(pooled, 0, 2 * GG * HH * 4, stream);
    hipMemsetAsync(cnt, 0, 2 * GG * 4, stream);

    k_packw<<<(3 * 832 * 64 + 255) / 256, 256, 0, stream>>>(Wq, Wk, Wv, Ws, panel);
    k_packemb<<<(64 * 256 + 255) / 256, 256, 0, stream>>>(W_emb, panelE);

    const size_t sQ  = dual ? (size_t)N * 256 : 0;
    const size_t sKV = dual ? (size_t)N * 512 : 0;
    const size_t sH  = dual ? (size_t)N * HH : 0;
    const size_t sC  = dual ? (size_t)N : 0;
    const size_t sP  = dual ? (size_t)(N + 1) : 0;
    const size_t sE  = dual ? (size_t)E : 0;

    const int passes = dual ? 1 : 2;
    for (int pass = 0; pass < passes; ++pass) {
        const float* xa   = dual ? x1 : (pass ? x2 : x1);
        const float* xb   = dual ? x2 : xa;
        const int* eia    = dual ? ei1 : (pass ? ei2 : ei1);
        const int* eib    = dual ? ei2 : eia;
        const int* bta    = dual ? bat1 : (pass ? bat2 : bat1);
        const int* btb    = dual ? bat2 : bta;
        const float* tmb  = dual ? temb : temb + (size_t)pass * HH;
        const int brBase  = dual ? 0 : pass;

        hipMemsetAsync(counts, 0, (size_t)NB * N * 4, stream);
        k_hist<<<dim3((E + 255) / 256, NB), 256, 0, stream>>>(eia, eib, E, counts, sC);
        k_scan<<<dim3(1, NB), 1024, 0, stream>>>(counts, N, indptr, cursor, sC, sP);
        k_scatter<<<dim3((E + 255) / 256, NB), 256, 0, stream>>>(eia, eib, E, cursor, srcs, sC, sE);

        k_embed<<<dim3((N + 31) / 32, NB), 256, 0, stream>>>(xa, xb, panelE, b_emb, tmb, h, N, sH);

        for (int l = 0; l < LLAY; ++l) {
            k_proj<<<dim3((N + 31) / 32, NB), 256, 0, stream>>>(
                h, panel + (size_t)l * 2 * 832 * 64,
                bq + (size_t)l * 256, bk + (size_t)l * 256, bv + (size_t)l * 256, bs + (size_t)l * 64,
                qb, kvb, skip, N, sH, sQ, sKV, sH);
            k_attn<<<dim3((N + 3) / 4, NB), 256, 0, stream>>>(
                qb, kvb, skip, indptr, srcs, h, N, sQ, sKV, sH, sH, sP, sE);
        }
        k_pool<<<dim3((N + 31) / 32, NB), 64, 0, stream>>>(h, bta, btb, pooled, cnt, N, sH, brBase);
    }

    k_head<<<GG, 64, 0, stream>>>(pooled, cnt, miw, mib, mow, mob, Wc1, bc1, Wc2, bc2,
                                  (float*)d_out);
}

// Round 5
// 609.850 us; speedup vs baseline: 3.3862x; 1.0746x over previous
//
#include <hip/hip_runtime.h>
#include <math.h>

#define FF   256
#define HH   64
#define NHEADS 4
#define LLAY 3
#define GG   64
#define CCLS 10

typedef __attribute__((ext_vector_type(8))) short short8v;
typedef __attribute__((ext_vector_type(4))) float floatx4;
typedef __attribute__((ext_vector_type(2))) _Float16 h2v;

#if defined(__has_builtin)
#if __has_builtin(__builtin_amdgcn_fdot2)
#define HAS_FDOT2 1
#endif
#endif

__device__ __forceinline__ unsigned short f2bf(float f) {
    unsigned int u = __float_as_uint(f);
    unsigned int r = (u + 0x7fffu + ((u >> 16) & 1u)) >> 16;   // RNE
    return (unsigned short)r;
}
__device__ __forceinline__ float bf2f(unsigned short h) {
    return __uint_as_float((unsigned int)h << 16);
}
__device__ __forceinline__ unsigned short f2h(float f) {
    _Float16 h = (_Float16)f;
    return __builtin_bit_cast(unsigned short, h);
}
__device__ __forceinline__ float2 h2f(unsigned int u) {
    h2v h = __builtin_bit_cast(h2v, u);
    return make_float2((float)h.x, (float)h.y);
}
__device__ __forceinline__ float dot8h(uint4 k, uint4 q) {
#ifdef HAS_FDOT2
    float d = 0.f;
    d = __builtin_amdgcn_fdot2(__builtin_bit_cast(h2v, k.x), __builtin_bit_cast(h2v, q.x), d, false);
    d = __builtin_amdgcn_fdot2(__builtin_bit_cast(h2v, k.y), __builtin_bit_cast(h2v, q.y), d, false);
    d = __builtin_amdgcn_fdot2(__builtin_bit_cast(h2v, k.z), __builtin_bit_cast(h2v, q.z), d, false);
    d = __builtin_amdgcn_fdot2(__builtin_bit_cast(h2v, k.w), __builtin_bit_cast(h2v, q.w), d, false);
    return d;
#else
    float2 k0 = h2f(k.x), k1 = h2f(k.y), k2 = h2f(k.z), k3 = h2f(k.w);
    float2 q0 = h2f(q.x), q1 = h2f(q.y), q2 = h2f(q.z), q3 = h2f(q.w);
    return k0.x*q0.x + k0.y*q0.y + k1.x*q1.x + k1.y*q1.y +
           k2.x*q2.x + k2.y*q2.y + k3.x*q3.x + k3.y*q3.y;
#endif
}

// ---------------------------------------------------------------------------
// Weight packing (bf16 hi/lo panels for MFMA GEMMs)
// ---------------------------------------------------------------------------
__global__ void k_packw(const float* __restrict__ Wq, const float* __restrict__ Wk,
                        const float* __restrict__ Wv, const float* __restrict__ Ws,
                        unsigned short* __restrict__ panel) {
    int idx = blockIdx.x * 256 + threadIdx.x;          // over 3*832*64
    if (idx >= 3 * 832 * 64) return;
    int l = idx / (832 * 64);
    int rem = idx % (832 * 64);
    int c = rem / 64, k = rem % 64;
    float v;
    if (c < 256)      v = Wq[((size_t)l * 64 + k) * 256 + c];
    else if (c < 512) v = Wk[((size_t)l * 64 + k) * 256 + (c - 256)];
    else if (c < 768) v = Wv[((size_t)l * 64 + k) * 256 + (c - 512)];
    else              v = Ws[((size_t)l * 64 + k) * 64 + (c - 768)];
    unsigned short hi = f2bf(v);
    unsigned short lo = f2bf(v - bf2f(hi));
    panel[((size_t)l * 2 + 0) * 832 * 64 + rem] = hi;
    panel[((size_t)l * 2 + 1) * 832 * 64 + rem] = lo;
}

__global__ void k_packemb(const float* __restrict__ W, unsigned short* __restrict__ pE) {
    int idx = blockIdx.x * 256 + threadIdx.x;          // over 64*256
    if (idx >= 64 * 256) return;
    int c = idx / 256, k = idx % 256;
    float v = W[(size_t)k * 64 + c];
    unsigned short hi = f2bf(v);
    unsigned short lo = f2bf(v - bf2f(hi));
    pE[idx] = hi;
    pE[64 * 256 + idx] = lo;
}

// ---------------------------------------------------------------------------
// CSR build, both branches at once (br = blockIdx.y)
// ---------------------------------------------------------------------------
__global__ void k_hist(const int* __restrict__ eiA, const int* __restrict__ eiB, int E,
                       int* __restrict__ counts0, int N) {
    int br = blockIdx.y;
    const int* dst = (br ? eiB : eiA) + E;
    int* c = counts0 + (size_t)br * N;
    int i = blockIdx.x * blockDim.x + threadIdx.x;
    if (i < E) atomicAdd(&c[dst[i]], 1);
}

// parallel scan over counts: per-1024 block exclusive scans + block totals
__global__ void k_scan_part(const int* __restrict__ counts0, int N,
                            int* __restrict__ indptr0, int* __restrict__ btot) {
    int br = blockIdx.y, b = blockIdx.x, t = threadIdx.x;
    const int* counts = counts0 + (size_t)br * N;
    int* indptr = indptr0 + (size_t)br * (N + 1);
    __shared__ int sd[1024];
    int i = b * 1024 + t;
    int v = (i < N) ? counts[i] : 0;
    sd[t] = v;
    __syncthreads();
    for (int off = 1; off < 1024; off <<= 1) {
        int x = (t >= off) ? sd[t - off] : 0;
        __syncthreads();
        sd[t] += x;
        __syncthreads();
    }
    if (i < N) indptr[i] = sd[t] - v;                  // local exclusive
    if (t == 1023) btot[br * 32 + b] = sd[1023];       // block total (nb <= 32)
}

__global__ void k_scan_fix(int N, int nb, int* __restrict__ indptr0,
                           int* __restrict__ cursor0, const int* __restrict__ btot) {
    int br = blockIdx.y, b = blockIdx.x, t = threadIdx.x;
    int* indptr = indptr0 + (size_t)br * (N + 1);
    int* cursor = cursor0 + (size_t)br * N;
    __shared__ int soff;
    if (t == 0) {
        int s = 0;
        for (int j = 0; j < b; ++j) s += btot[br * 32 + j];
        soff = s;
        if (b == nb - 1) indptr[N] = s + btot[br * 32 + b];
    }
    __syncthreads();
    int i = b * 1024 + t;
    if (i < N) {
        int val = indptr[i] + soff;
        indptr[i] = val;
        cursor0[(size_t)br * N + i] = val;
    }
    (void)cursor;
}

__global__ void k_scatter(const int* __restrict__ eiA, const int* __restrict__ eiB, int E,
                          int* __restrict__ cursor0, int* __restrict__ srcs0, int N) {
    int br = blockIdx.y;
    const int* ei = br ? eiB : eiA;
    int* cursor = cursor0 + (size_t)br * N;
    int* srcs = srcs0 + (size_t)br * E;
    int i = blockIdx.x * blockDim.x + threadIdx.x;
    if (i < E) {
        int p = atomicAdd(&cursor[ei[E + i]], 1);
        srcs[p] = ei[i];
    }
}

// ---------------------------------------------------------------------------
// Embedding MFMA: h[br] = x @ W_emb + b + temb[br].  M=32/block, both branches.
// ---------------------------------------------------------------------------
__global__ void k_embed(const float* __restrict__ xa, const float* __restrict__ xb,
                        const unsigned short* __restrict__ pE,
                        const float* __restrict__ bemb, const float* __restrict__ temb,
                        float* __restrict__ h0, int N) {
    int br = blockIdx.y;
    const float* x = br ? xb : xa;
    float* h = h0 + (size_t)br * N * HH;
    int t = threadIdx.x, lane = t & 63, wid = t >> 6;
    int arow = lane & 15, kg = lane >> 4;
    int mbase = blockIdx.x * 32;
    int n0 = min(mbase + arow, N - 1);
    int n1 = min(mbase + 16 + arow, N - 1);
    const float* x0 = x + (size_t)n0 * FF + kg * 8;
    const float* x1 = x + (size_t)n1 * FF + kg * 8;
    const unsigned short* bh = pE + (size_t)(wid * 16 + arow) * FF + kg * 8;
    const unsigned short* bl = bh + 64 * FF;
    floatx4 acc0 = {0.f, 0.f, 0.f, 0.f}, acc1 = {0.f, 0.f, 0.f, 0.f};
#pragma unroll
    for (int ks = 0; ks < 8; ++ks) {
        const float4* p0 = reinterpret_cast<const float4*>(x0 + ks * 32);
        float4 f00 = p0[0], f01 = p0[1];
        const float4* p1 = reinterpret_cast<const float4*>(x1 + ks * 32);
        float4 f10 = p1[0], f11 = p1[1];
        float v0[8] = {f00.x, f00.y, f00.z, f00.w, f01.x, f01.y, f01.z, f01.w};
        float v1[8] = {f10.x, f10.y, f10.z, f10.w, f11.x, f11.y, f11.z, f11.w};
        short8v a0h, a0l, a1h, a1l;
#pragma unroll
        for (int i = 0; i < 8; ++i) {
            unsigned short h0v = f2bf(v0[i]);
            a0h[i] = (short)h0v; a0l[i] = (short)f2bf(v0[i] - bf2f(h0v));
            unsigned short h1v = f2bf(v1[i]);
            a1h[i] = (short)h1v; a1l[i] = (short)f2bf(v1[i] - bf2f(h1v));
        }
        short8v bhv = *reinterpret_cast<const short8v*>(bh + ks * 32);
        short8v blv = *reinterpret_cast<const short8v*>(bl + ks * 32);
        acc0 = __builtin_amdgcn_mfma_f32_16x16x32_bf16(a0h, bhv, acc0, 0, 0, 0);
        acc0 = __builtin_amdgcn_mfma_f32_16x16x32_bf16(a0l, bhv, acc0, 0, 0, 0);
        acc0 = __builtin_amdgcn_mfma_f32_16x16x32_bf16(a0h, blv, acc0, 0, 0, 0);
        acc1 = __builtin_amdgcn_mfma_f32_16x16x32_bf16(a1h, bhv, acc1, 0, 0, 0);
        acc1 = __builtin_amdgcn_mfma_f32_16x16x32_bf16(a1l, bhv, acc1, 0, 0, 0);
        acc1 = __builtin_amdgcn_mfma_f32_16x16x32_bf16(a1h, blv, acc1, 0, 0, 0);
    }
    int col = wid * 16 + (lane & 15);
    float bias = bemb[col] + temb[(size_t)br * HH + col];
#pragma unroll
    for (int r = 0; r < 4; ++r) {
        int row0 = mbase + kg * 4 + r;
        if (row0 < N) h[(size_t)row0 * HH + col] = acc0[r] + bias;
        int row1 = mbase + 16 + kg * 4 + r;
        if (row1 < N) h[(size_t)row1 * HH + col] = acc1[r] + bias;
    }
}

// ---------------------------------------------------------------------------
// Projection MFMA: q/k/v (fp16) + skip (written back into h, f32).
// brBase+blockIdx.y = real branch (h); blockIdx.y = buffer slot (qb/kvb).
// ---------------------------------------------------------------------------
__global__ void k_proj(float* __restrict__ h0, const unsigned short* __restrict__ panel,
                       const float* __restrict__ bq, const float* __restrict__ bk,
                       const float* __restrict__ bv, const float* __restrict__ bs,
                       unsigned short* __restrict__ qb0, unsigned short* __restrict__ kvb0,
                       int N, int brBase, size_t sQ, size_t sKV) {
    int slot = blockIdx.y;
    int br = brBase + slot;
    float* h = h0 + (size_t)br * N * HH;
    unsigned short* q = qb0 + (size_t)slot * sQ;
    unsigned short* kv = kvb0 + (size_t)slot * sKV;
    int t = threadIdx.x, lane = t & 63, wid = t >> 6;
    int arow = lane & 15, kg = lane >> 4;
    int mbase = blockIdx.x * 32;

    short8v Ah[2][2], Al[2][2];
#pragma unroll
    for (int mt = 0; mt < 2; ++mt) {
        int node = min(mbase + mt * 16 + arow, N - 1);
        const float* src = h + (size_t)node * HH + kg * 8;
#pragma unroll
        for (int ks = 0; ks < 2; ++ks) {
            const float4* pp = reinterpret_cast<const float4*>(src + ks * 32);
            float4 fa = pp[0], fb = pp[1];
            float v[8] = {fa.x, fa.y, fa.z, fa.w, fb.x, fb.y, fb.z, fb.w};
#pragma unroll
            for (int i = 0; i < 8; ++i) {
                unsigned short hi = f2bf(v[i]);
                Ah[mt][ks][i] = (short)hi;
                Al[mt][ks][i] = (short)f2bf(v[i] - bf2f(hi));
            }
        }
    }
    // all waves have consumed h (A fragments in regs) before wave 3 overwrites
    // h rows with skip below
    __syncthreads();

    const unsigned short* ph = panel;
    const unsigned short* pl = panel + 832 * 64;
#pragma unroll
    for (int j = 0; j < 13; ++j) {
        int nt = wid * 13 + j;
        size_t boff = (size_t)(nt * 16 + arow) * 64 + kg * 8;
        floatx4 acc0 = {0.f, 0.f, 0.f, 0.f}, acc1 = {0.f, 0.f, 0.f, 0.f};
#pragma unroll
        for (int ks = 0; ks < 2; ++ks) {
            short8v bh = *reinterpret_cast<const short8v*>(ph + boff + ks * 32);
            short8v bl = *reinterpret_cast<const short8v*>(pl + boff + ks * 32);
            acc0 = __builtin_amdgcn_mfma_f32_16x16x32_bf16(Ah[0][ks], bh, acc0, 0, 0, 0);
            acc0 = __builtin_amdgcn_mfma_f32_16x16x32_bf16(Al[0][ks], bh, acc0, 0, 0, 0);
            acc0 = __builtin_amdgcn_mfma_f32_16x16x32_bf16(Ah[0][ks], bl, acc0, 0, 0, 0);
            acc1 = __builtin_amdgcn_mfma_f32_16x16x32_bf16(Ah[1][ks], bh, acc1, 0, 0, 0);
            acc1 = __builtin_amdgcn_mfma_f32_16x16x32_bf16(Al[1][ks], bh, acc1, 0, 0, 0);
            acc1 = __builtin_amdgcn_mfma_f32_16x16x32_bf16(Ah[1][ks], bl, acc1, 0, 0, 0);
        }
        int col = nt * 16 + (lane & 15);
        float bias;
        if (col < 256) bias = bq[col];
        else if (col < 512) bias = bk[col - 256];
        else if (col < 768) bias = bv[col - 512];
        else bias = bs[col - 768];

        auto store_tile = [&](const floatx4& acc, int mrow0) {
#pragma unroll
            for (int r = 0; r < 4; ++r) {
                int node = mrow0 + kg * 4 + r;
                if (node < N) {
                    float val = acc[r] + bias;
                    if (col < 256)      q[(size_t)node * 256 + col] = f2h(val);
                    else if (col < 512) kv[(size_t)node * 512 + (col - 256)] = f2h(val);
                    else if (col < 768) kv[(size_t)node * 512 + 256 + (col - 512)] = f2h(val);
                    else                h[(size_t)node * HH + (col - 768)] = val;  // skip
                }
            }
        };
        store_tile(acc0, mbase);
        store_tile(acc1, mbase + 16);
    }
}

// ---------------------------------------------------------------------------
// Attention aggregate. One wave per node; 32 lanes per edge (2 edges/pass).
// lane: half=l>>5, head=(l&31)>>3, octet o=(l&7) -> dims [head*64+o*8 .. +7].
// fp16 K/V/q; v_dot2 K-dots; two independent online-softmax halves merged at
// the end via shfl_xor(32). Reads skip from h[n] and overwrites h[n] with
// relu(head_mean + skip).
// ---------------------------------------------------------------------------
__global__ void k_attn(const unsigned short* __restrict__ qb0,
                       const unsigned short* __restrict__ kvb0,
                       const int* __restrict__ indptr0, const int* __restrict__ srcs0,
                       float* __restrict__ h0, int N, int E, int brBase,
                       size_t sQ, size_t sKV) {
    int slot = blockIdx.y;
    int br = brBase + slot;
    const unsigned short* qb = qb0 + (size_t)slot * sQ;
    const unsigned short* kvb = kvb0 + (size_t)slot * sKV;
    const int* indptr = indptr0 + (size_t)br * (N + 1);
    const int* srcs = srcs0 + (size_t)br * E;
    float* h = h0 + (size_t)br * N * HH;

    int t = threadIdx.x;
    int lane = t & 63;
    int half = lane >> 5;
    int il = lane & 31;
    int o = il & 7;
    int elemoff = (il >> 3) * 64 + o * 8;

    int wvg = blockIdx.x * 4 + (t >> 6);
    int nw = gridDim.x * 4;
    for (int n = wvg; n < N; n += nw) {
        int beg = indptr[n], end = indptr[n + 1];
        if (end == beg) {
            if (lane < 8) {
                float4 s0 = *reinterpret_cast<const float4*>(&h[(size_t)n * HH + o * 8]);
                float4 s1 = *reinterpret_cast<const float4*>(&h[(size_t)n * HH + o * 8 + 4]);
                s0.x = fmaxf(s0.x, 0.f); s0.y = fmaxf(s0.y, 0.f);
                s0.z = fmaxf(s0.z, 0.f); s0.w = fmaxf(s0.w, 0.f);
                s1.x = fmaxf(s1.x, 0.f); s1.y = fmaxf(s1.y, 0.f);
                s1.z = fmaxf(s1.z, 0.f); s1.w = fmaxf(s1.w, 0.f);
                *reinterpret_cast<float4*>(&h[(size_t)n * HH + o * 8]) = s0;
                *reinterpret_cast<float4*>(&h[(size_t)n * HH + o * 8 + 4]) = s1;
            }
            continue;
        }
        uint4 q4 = *reinterpret_cast<const uint4*>(qb + (size_t)n * 256 + elemoff);
        float m = -INFINITY, s = 0.f;
        float a0=0.f,a1=0.f,a2=0.f,a3=0.f,a4=0.f,a5=0.f,a6=0.f,a7=0.f;

        for (int e0 = beg; e0 < end; e0 += 8) {
            uint4 kk[4], vv[4];
            bool vd[4];
            // issue all gathers for 4 edges of this half
#pragma unroll
            for (int i = 0; i < 4; ++i) {
                int ei = e0 + 2 * i + half;
                bool ok = ei < end;
                vd[i] = ok;
                int src = srcs[ok ? ei : beg];
                const unsigned short* kb = kvb + ((size_t)src << 9) + elemoff;
                kk[i] = *reinterpret_cast<const uint4*>(kb);
                vv[i] = *reinterpret_cast<const uint4*>(kb + 256);
            }
            float lg[4];
#pragma unroll
            for (int i = 0; i < 4; ++i) {
                float d = dot8h(kk[i], q4);
                d += __shfl_xor(d, 1);
                d += __shfl_xor(d, 2);
                d += __shfl_xor(d, 4);
                lg[i] = vd[i] ? d * 0.125f : -INFINITY;
            }
            float cm = fmaxf(fmaxf(lg[0], lg[1]), fmaxf(lg[2], lg[3]));
            float mn = fmaxf(m, cm);
            float rs = (m == -INFINITY) ? 0.f : __expf(m - mn);
            s *= rs;
            a0*=rs; a1*=rs; a2*=rs; a3*=rs; a4*=rs; a5*=rs; a6*=rs; a7*=rs;
            m = mn;
#pragma unroll
            for (int i = 0; i < 4; ++i) {
                float p = vd[i] ? __expf(lg[i] - mn) : 0.f;
                s += p;
                float2 v01 = h2f(vv[i].x), v23 = h2f(vv[i].y);
                float2 v45 = h2f(vv[i].z), v67 = h2f(vv[i].w);
                a0 += p * v01.x; a1 += p * v01.y; a2 += p * v23.x; a3 += p * v23.y;
                a4 += p * v45.x; a5 += p * v45.y; a6 += p * v67.x; a7 += p * v67.y;
            }
        }
        // merge the two halves (independent online softmaxes)
        float mo = __shfl_xor(m, 32);
        float mt = fmaxf(m, mo);
        float myscale = (m == -INFINITY) ? 0.f : __expf(m - mt);
        float ss = s * myscale;
        float st = ss + __shfl_xor(ss, 32);
        float inv = 1.f / st;
        a0 *= myscale; a0 += __shfl_xor(a0, 32);
        a1 *= myscale; a1 += __shfl_xor(a1, 32);
        a2 *= myscale; a2 += __shfl_xor(a2, 32);
        a3 *= myscale; a3 += __shfl_xor(a3, 32);
        a4 *= myscale; a4 += __shfl_xor(a4, 32);
        a5 *= myscale; a5 += __shfl_xor(a5, 32);
        a6 *= myscale; a6 += __shfl_xor(a6, 32);
        a7 *= myscale; a7 += __shfl_xor(a7, 32);
        a0 *= inv; a1 *= inv; a2 *= inv; a3 *= inv;
        a4 *= inv; a5 *= inv; a6 *= inv; a7 *= inv;
        // head mean (sum over head bits 3,4 of il)
        a0 += __shfl_xor(a0, 8);  a0 += __shfl_xor(a0, 16);
        a1 += __shfl_xor(a1, 8);  a1 += __shfl_xor(a1, 16);
        a2 += __shfl_xor(a2, 8);  a2 += __shfl_xor(a2, 16);
        a3 += __shfl_xor(a3, 8);  a3 += __shfl_xor(a3, 16);
        a4 += __shfl_xor(a4, 8);  a4 += __shfl_xor(a4, 16);
        a5 += __shfl_xor(a5, 8);  a5 += __shfl_xor(a5, 16);
        a6 += __shfl_xor(a6, 8);  a6 += __shfl_xor(a6, 16);
        a7 += __shfl_xor(a7, 8);  a7 += __shfl_xor(a7, 16);
        if (lane < 8) {
            float4 s0 = *reinterpret_cast<const float4*>(&h[(size_t)n * HH + o * 8]);
            float4 s1 = *reinterpret_cast<const float4*>(&h[(size_t)n * HH + o * 8 + 4]);
            float4 r0, r1;
            r0.x = fmaxf(0.25f * a0 + s0.x, 0.f);
            r0.y = fmaxf(0.25f * a1 + s0.y, 0.f);
            r0.z = fmaxf(0.25f * a2 + s0.z, 0.f);
            r0.w = fmaxf(0.25f * a3 + s0.w, 0.f);
            r1.x = fmaxf(0.25f * a4 + s1.x, 0.f);
            r1.y = fmaxf(0.25f * a5 + s1.y, 0.f);
            r1.z = fmaxf(0.25f * a6 + s1.z, 0.f);
            r1.w = fmaxf(0.25f * a7 + s1.w, 0.f);
            *reinterpret_cast<float4*>(&h[(size_t)n * HH + o * 8]) = r0;
            *reinterpret_cast<float4*>(&h[(size_t)n * HH + o * 8 + 4]) = r1;
        }
    }
}

// ---------------------------------------------------------------------------
// Mean pool (batch sorted, run-length accumulate), both branches
// ---------------------------------------------------------------------------
__global__ void k_pool(const float* __restrict__ h0, const int* __restrict__ batA,
                       const int* __restrict__ batB,
                       float* __restrict__ pooled, float* __restrict__ cnt, int N) {
    int br = blockIdx.y;
    const float* h = h0 + (size_t)br * N * HH;
    const int* batch = br ? batB : batA;
    float* pb = pooled + (size_t)br * GG * HH;
    float* cb = cnt + (size_t)br * GG;
    int j = threadIdx.x;
    int n0 = blockIdx.x * 32;
    int n1 = min(n0 + 32, N);
    if (n0 >= N) return;
    float acc = 0.f;
    int c = 0;
    int gcur = batch[n0];
    for (int n = n0; n < n1; ++n) {
        int g = batch[n];
        if (g != gcur) {
            atomicAdd(&pb[gcur * HH + j], acc);
            if (j == 0) atomicAdd(&cb[gcur], (float)c);
            acc = 0.f; c = 0; gcur = g;
        }
        acc += h[(size_t)n * HH + j];
        ++c;
    }
    atomicAdd(&pb[gcur * HH + j], acc);
    if (j == 0) atomicAdd(&cb[gcur], (float)c);
}

// ---------------------------------------------------------------------------
// Head: mean-pool finalize, MHA over seq=2, mean, classifier. Block per graph.
// ---------------------------------------------------------------------------
__global__ void k_head(const float* __restrict__ pooled, const float* __restrict__ cnt,
                       const float* __restrict__ in_w, const float* __restrict__ in_b,
                       const float* __restrict__ out_w, const float* __restrict__ out_b,
                       const float* __restrict__ Wc1, const float* __restrict__ bc1,
                       const float* __restrict__ Wc2, const float* __restrict__ bc2,
                       float* __restrict__ out) {
    int g = blockIdx.x;
    int t = threadIdx.x;
    __shared__ float xs[2][HH];
    __shared__ float qkvs[2][3 * HH];
    __shared__ float sc[2][2][NHEADS];
    __shared__ float os[2][HH];
    __shared__ float xf[HH];
    __shared__ float r1[HH / 2];

    for (int s = 0; s < 2; ++s) {
        float c = fmaxf(cnt[s * GG + g], 1.f);
        xs[s][t] = pooled[(size_t)s * GG * HH + g * HH + t] / c;
    }
    __syncthreads();
    for (int idx = t; idx < 2 * 192; idx += 64) {
        int s = idx / 192, i = idx % 192;
        float a = in_b[i];
#pragma unroll 8
        for (int j = 0; j < HH; ++j) a += xs[s][j] * in_w[i * HH + j];
        qkvs[s][i] = a;
    }
    __syncthreads();
    if (t < 16) {
        int s1 = t >> 3, s2 = (t >> 2) & 1, hh = t & 3;
        float a = 0.f;
#pragma unroll
        for (int d = 0; d < 16; ++d) a += qkvs[s1][hh * 16 + d] * qkvs[s2][HH + hh * 16 + d];
        sc[s1][s2][hh] = a * 0.25f;
    }
    __syncthreads();
    {
        int hh = t >> 4;
        for (int s1 = 0; s1 < 2; ++s1) {
            float a0 = sc[s1][0][hh], a1 = sc[s1][1][hh];
            float mx = fmaxf(a0, a1);
            float e0 = __expf(a0 - mx), e1 = __expf(a1 - mx);
            float inv = 1.f / (e0 + e1);
            os[s1][t] = (e0 * inv) * qkvs[0][2 * HH + t] + (e1 * inv) * qkvs[1][2 * HH + t];
        }
    }
    __syncthreads();
    {
        float acc0 = 0.f, acc1 = 0.f;
#pragma unroll 8
        for (int k2 = 0; k2 < HH; ++k2) {
            float w = out_w[t * HH + k2];
            acc0 += os[0][k2] * w;
            acc1 += os[1][k2] * w;
        }
        xf[t] = 0.5f * (acc0 + acc1) + out_b[t];
    }
    __syncthreads();
    if (t < 32) {
        float a = bc1[t];
#pragma unroll 8
        for (int j = 0; j < HH; ++j) a += xf[j] * Wc1[j * 32 + t];
        r1[t] = fmaxf(a, 0.f);
    }
    __syncthreads();
    if (t < CCLS) {
        float a = bc2[t];
#pragma unroll
        for (int j2 = 0; j2 < 32; ++j2) a += r1[j2] * Wc2[j2 * CCLS + t];
        out[g * CCLS + t] = a;
    }
}

// ---------------------------------------------------------------------------
extern "C" void kernel_launch(void* const* d_in, const int* in_sizes, int n_in,
                              void* d_out, int out_size, void* d_ws, size_t ws_size,
                              hipStream_t stream) {
    const float* x1    = (const float*)d_in[0];
    const float* x2    = (const float*)d_in[1];
    const int*   ei1   = (const int*)d_in[2];
    const int*   ei2   = (const int*)d_in[3];
    const int*   bat1  = (const int*)d_in[4];
    const int*   bat2  = (const int*)d_in[5];
    const float* W_emb = (const float*)d_in[6];
    const float* b_emb = (const float*)d_in[7];
    const float* temb  = (const float*)d_in[8];
    const float* Wq    = (const float*)d_in[9];
    const float* bq    = (const float*)d_in[10];
    const float* Wk    = (const float*)d_in[11];
    const float* bk    = (const float*)d_in[12];
    const float* Wv    = (const float*)d_in[13];
    const float* bv    = (const float*)d_in[14];
    const float* Ws    = (const float*)d_in[15];
    const float* bs    = (const float*)d_in[16];
    const float* miw   = (const float*)d_in[17];
    const float* mib   = (const float*)d_in[18];
    const float* mow   = (const float*)d_in[19];
    const float* mob   = (const float*)d_in[20];
    const float* Wc1   = (const float*)d_in[21];
    const float* bc1   = (const float*)d_in[22];
    const float* Wc2   = (const float*)d_in[23];
    const float* bc2   = (const float*)d_in[24];

    const int N = in_sizes[4];        // 20000
    const int E = in_sizes[2] / 2;    // 320000

    // footprint for NBs qkv-buffer slots (h always holds both branches)
    auto need = [&](int NBs) -> size_t {
        auto al = [](size_t b) { return (b + 255) & ~(size_t)255; };
        size_t s = 0;
        s += al((size_t)2 * N * HH * 4);            // h (both branches)
        s += al((size_t)NBs * N * 256 * 2);         // qb fp16
        s += al((size_t)NBs * N * 512 * 2);         // kvb fp16
        s += al((size_t)2 * GG * HH * 4);           // pooled
        s += al((size_t)2 * GG * 4);                // cnt
        s += al((size_t)2 * N * 4);                 // counts
        s += al((size_t)2 * (N + 1) * 4);           // indptr
        s += al((size_t)2 * N * 4);                 // cursor
        s += al((size_t)2 * E * 4);                 // srcs
        s += al((size_t)64 * 4);                    // btot
        s += al((size_t)3 * 2 * 832 * 64 * 2);      // panel
        s += al((size_t)2 * 64 * 256 * 2);          // panelE
        return s;
    };
    const bool dual = ws_size >= need(2);
    const int NBs = dual ? 2 : 1;

    char* p = (char*)d_ws;
    auto carve = [&](size_t bytes) {
        void* r = (void*)p;
        p += (bytes + 255) & ~(size_t)255;
        return r;
    };
    float*          h      = (float*)carve((size_t)2 * N * HH * 4);
    unsigned short* qb     = (unsigned short*)carve((size_t)NBs * N * 256 * 2);
    unsigned short* kvb    = (unsigned short*)carve((size_t)NBs * N * 512 * 2);
    float*          pooled = (float*)carve((size_t)2 * GG * HH * 4);
    float*          cnt    = (float*)carve((size_t)2 * GG * 4);
    int*            counts = (int*)carve((size_t)2 * N * 4);
    int*            indptr = (int*)carve((size_t)2 * (N + 1) * 4);
    int*            cursor = (int*)carve((size_t)2 * N * 4);
    int*            srcs   = (int*)carve((size_t)2 * E * 4);
    int*            btot   = (int*)carve((size_t)64 * 4);
    unsigned short* panel  = (unsigned short*)carve((size_t)3 * 2 * 832 * 64 * 2);
    unsigned short* panelE = (unsigned short*)carve((size_t)2 * 64 * 256 * 2);

    hipMemsetAsync(pooled, 0, (size_t)2 * GG * HH * 4, stream);
    hipMemsetAsync(cnt, 0, (size_t)2 * GG * 4, stream);
    hipMemsetAsync(counts, 0, (size_t)2 * N * 4, stream);

    k_packw<<<(3 * 832 * 64 + 255) / 256, 256, 0, stream>>>(Wq, Wk, Wv, Ws, panel);
    k_packemb<<<(64 * 256 + 255) / 256, 256, 0, stream>>>(W_emb, panelE);

    const int nb = (N + 1023) / 1024;           // <= 32 (N <= 32768)
    k_hist<<<dim3((E + 255) / 256, 2), 256, 0, stream>>>(ei1, ei2, E, counts, N);
    k_scan_part<<<dim3(nb, 2), 1024, 0, stream>>>(counts, N, indptr, btot);
    k_scan_fix<<<dim3(nb, 2), 1024, 0, stream>>>(N, nb, indptr, cursor, btot);
    k_scatter<<<dim3((E + 255) / 256, 2), 256, 0, stream>>>(ei1, ei2, E, cursor, srcs, N);

    k_embed<<<dim3((N + 31) / 32, 2), 256, 0, stream>>>(x1, x2, panelE, b_emb, temb, h, N);

    const size_t sQ  = (size_t)N * 256;
    const size_t sKV = (size_t)N * 512;
    const int attnGX = min((N + 3) / 4, 2048);
    const int projGX = (N + 31) / 32;

    if (dual) {
        for (int l = 0; l < LLAY; ++l) {
            k_proj<<<dim3(projGX, 2), 256, 0, stream>>>(
                h, panel + (size_t)l * 2 * 832 * 64,
                bq + (size_t)l * 256, bk + (size_t)l * 256, bv + (size_t)l * 256, bs + (size_t)l * 64,
                qb, kvb, N, 0, sQ, sKV);
            k_attn<<<dim3(attnGX, 2), 256, 0, stream>>>(
                qb, kvb, indptr, srcs, h, N, E, 0, sQ, sKV);
        }
    } else {
        for (int br = 0; br < 2; ++br) {
            for (int l = 0; l < LLAY; ++l) {
                k_proj<<<dim3(projGX, 1), 256, 0, stream>>>(
                    h, panel + (size_t)l * 2 * 832 * 64,
                    bq + (size_t)l * 256, bk + (size_t)l * 256, bv + (size_t)l * 256, bs + (size_t)l * 64,
                    qb, kvb, N, br, sQ, sKV);
                k_attn<<<dim3(attnGX, 1), 256, 0, stream>>>(
                    qb, kvb, indptr, srcs, h, N, E, br, sQ, sKV);
            }
        }
    }

    k_pool<<<dim3((N + 31) / 32, 2), 64, 0, stream>>>(h, bat1, bat2, pooled, cnt, N);

    k_head<<<GG, 64, 0, stream>>>(pooled, cnt, miw, mib, mow, mob, Wc1, bc1, Wc2, bc2,
                                  (float*)d_out);
}